// Round 2
// baseline (804.096 us; speedup 1.0000x reference)
//
#include <hip/hip_runtime.h>
#include <hip/hip_bf16.h>

#define NV 100000
#define NE 20000
#define DD 128

using bf16 = __hip_bfloat16;
using bf16x2 = __hip_bfloat162;

typedef __attribute__((ext_vector_type(8))) short frag_ab;   // 8 bf16 in 4 VGPRs
typedef __attribute__((ext_vector_type(4))) float frag_cd;   // 4 fp32 acc

// ---------------- counting ----------------
__global__ void count_kernel(const int* __restrict__ src, const int* __restrict__ dst,
                             int* __restrict__ deg_v, int* __restrict__ cnt_e, int nnz) {
    int i = blockIdx.x * 256 + threadIdx.x;
    if (i < nnz) {
        atomicAdd(&deg_v[src[i]], 1);
        atomicAdd(&cnt_e[dst[i]], 1);
    }
}

// ---------------- 3-kernel exclusive scan (n <= 128*1024) ----------------
__global__ void scan_reduce(const int* __restrict__ in, int* __restrict__ part, int n) {
    __shared__ int sm[1024];
    int t = threadIdx.x;
    int i = blockIdx.x * 1024 + t;
    sm[t] = (i < n) ? in[i] : 0;
    __syncthreads();
    for (int ofs = 512; ofs > 0; ofs >>= 1) {
        if (t < ofs) sm[t] += sm[t + ofs];
        __syncthreads();
    }
    if (t == 0) part[blockIdx.x] = sm[0];
}

__global__ void scan_top(int* part, int nb) {
    __shared__ int sm[128];
    int t = threadIdx.x;  // 128 threads
    int v = (t < nb) ? part[t] : 0;
    sm[t] = v;
    __syncthreads();
    for (int ofs = 1; ofs < 128; ofs <<= 1) {
        int x = (t >= ofs) ? sm[t - ofs] : 0;
        __syncthreads();
        sm[t] += x;
        __syncthreads();
    }
    if (t < nb) part[t] = sm[t] - v;  // exclusive
}

__global__ void scan_write(const int* __restrict__ in, const int* __restrict__ part,
                           int* __restrict__ off, int* __restrict__ cur, int n) {
    __shared__ int sm[1024];
    int t = threadIdx.x;
    int i = blockIdx.x * 1024 + t;
    int v = (i < n) ? in[i] : 0;
    sm[t] = v;
    __syncthreads();
    for (int ofs = 1; ofs < 1024; ofs <<= 1) {
        int x = (t >= ofs) ? sm[t - ofs] : 0;
        __syncthreads();
        sm[t] += x;
        __syncthreads();
    }
    int incl = sm[t];
    int base = part[blockIdx.x];
    if (i < n) {
        int ex = base + incl - v;
        off[i] = ex;
        cur[i] = ex;
        if (i == n - 1) off[n] = base + incl;
    }
}

// ---------------- CSR fill (counting sort) ----------------
__global__ void fill_e(const int* __restrict__ src, const int* __restrict__ dst,
                       int* __restrict__ cur_e, int* __restrict__ e_src, int nnz) {
    int i = blockIdx.x * 256 + threadIdx.x;
    if (i < nnz) {
        int p = atomicAdd(&cur_e[dst[i]], 1);
        e_src[p] = src[i];
    }
}

__global__ void fill_v(const int* __restrict__ src, const int* __restrict__ dst,
                       int* __restrict__ cur_v, int* __restrict__ v_edge, int nnz) {
    int i = blockIdx.x * 256 + threadIdx.x;
    if (i < nnz) {
        int p = atomicAdd(&cur_v[src[i]], 1);
        v_edge[p] = dst[i];
    }
}

// ---------------- W (fp32) -> bf16 ----------------
__global__ void cvt_w(const float* __restrict__ W, bf16* __restrict__ Wb, int n) {
    int i = blockIdx.x * 256 + threadIdx.x;
    if (i < n) Wb[i] = __float2bfloat16(W[i]);
}

// ---------------- edge aggregation: S[e] = (De/cnt) * sum_{src in e} X[src] ----------------
__global__ void edge_agg(const float* __restrict__ X, const int* __restrict__ off_e,
                         const int* __restrict__ e_src, const int* __restrict__ deg_v,
                         bf16* __restrict__ S, float* __restrict__ beta) {
    int wave = (blockIdx.x * blockDim.x + threadIdx.x) >> 6;
    int lane = threadIdx.x & 63;
    if (wave >= NE) return;
    int start = off_e[wave], end = off_e[wave + 1];
    float ax = 0.f, ay = 0.f, degsum = 0.f;
    const float* Xl = X + lane * 2;
    for (int j = start; j < end; ++j) {
        int s = e_src[j];                         // wave-uniform load
        float2 x2 = *(const float2*)(Xl + (size_t)s * DD);
        ax += x2.x;
        ay += x2.y;
        degsum += (float)deg_v[s];
    }
    float cntf = (float)(end - start);
    float Des = degsum / (cntf + 1.0f);
    float De = (Des > 0.f) ? rsqrtf(fmaxf(Des, 1e-30f)) : 1.0f;
    float scale = De / fmaxf(cntf, 1.0f);
    bf16x2 s2;
    s2.x = __float2bfloat16(ax * scale);
    s2.y = __float2bfloat16(ay * scale);
    *((bf16x2*)(S + (size_t)wave * DD + lane * 2)) = s2;
    if (lane == 0) beta[wave] = (cntf > 0.f) ? De : 0.f;  // coefficient for b
}

// ---------------- GEMM: Y = S @ W^T + beta * b  (MFMA 16x16x32 bf16) ----------------
__global__ __launch_bounds__(256) void gemm_edge(const bf16* __restrict__ S, const bf16* __restrict__ Wb,
                                                 const float* __restrict__ bias, const float* __restrict__ beta,
                                                 bf16* __restrict__ Y) {
    int wave = (blockIdx.x * blockDim.x + threadIdx.x) >> 6;
    int lane = threadIdx.x & 63;
    int mBase = wave * 16;
    if (mBase >= NE) return;
    int l16 = lane & 15, quad = lane >> 4;

    const short* Ss = (const short*)S;
    const short* Ws = (const short*)Wb;

    frag_ab a[4];
#pragma unroll
    for (int kt = 0; kt < 4; ++kt)
        a[kt] = *(const frag_ab*)(Ss + (size_t)(mBase + l16) * DD + kt * 32 + quad * 8);

    float beta_r[4];
#pragma unroll
    for (int r = 0; r < 4; ++r) beta_r[r] = beta[mBase + quad * 4 + r];

#pragma unroll
    for (int nt = 0; nt < 8; ++nt) {
        frag_cd acc = {0.f, 0.f, 0.f, 0.f};
#pragma unroll
        for (int kt = 0; kt < 4; ++kt) {
            frag_ab bfr = *(const frag_ab*)(Ws + (size_t)(nt * 16 + l16) * DD + kt * 32 + quad * 8);
            acc = __builtin_amdgcn_mfma_f32_16x16x32_bf16(a[kt], bfr, acc, 0, 0, 0);
        }
        float bv = bias[nt * 16 + l16];
#pragma unroll
        for (int r = 0; r < 4; ++r) {
            int row = mBase + quad * 4 + r;
            float v = acc[r] + beta_r[r] * bv;
            Y[(size_t)row * DD + nt * 16 + l16] = __float2bfloat16(v);
        }
    }
}

// ---------------- vertex aggregation + norm + relu ----------------
__global__ void vertex_agg(const bf16* __restrict__ Y, const int* __restrict__ off_v,
                           const int* __restrict__ v_edge, float* __restrict__ out) {
    int wave = (blockIdx.x * blockDim.x + threadIdx.x) >> 6;
    int lane = threadIdx.x & 63;
    if (wave >= NV) return;
    int start = off_v[wave], end = off_v[wave + 1];
    float ax = 0.f, ay = 0.f;
    const bf16* Yl = Y + lane * 2;
    for (int j = start; j < end; ++j) {
        int e = v_edge[j];
        bf16x2 y2 = *(const bf16x2*)(Yl + (size_t)e * DD);
        ax += __bfloat162float(y2.x);
        ay += __bfloat162float(y2.y);
    }
    int deg = end - start;
    float dvn = (deg > 0) ? rsqrtf((float)deg) : 0.f;
    float2 o;
    o.x = fmaxf(ax * dvn, 0.f);
    o.y = fmaxf(ay * dvn, 0.f);
    *((float2*)(out + (size_t)wave * DD + lane * 2)) = o;
}

extern "C" void kernel_launch(void* const* d_in, const int* in_sizes, int n_in,
                              void* d_out, int out_size, void* d_ws, size_t ws_size,
                              hipStream_t stream) {
    const float* X = (const float*)d_in[0];
    const float* W = (const float*)d_in[1];
    const float* b = (const float*)d_in[2];
    const int* src = (const int*)d_in[3];
    const int* dst = (const int*)d_in[4];
    int nnz = in_sizes[3];

    char* ws = (char*)d_ws;
    size_t o = 0;
    auto take = [&](size_t bytes) -> char* {
        char* p = ws + o;
        o += (bytes + 255) & ~(size_t)255;
        return p;
    };
    int* deg_v = (int*)take((size_t)NV * 4);
    int* cnt_e = (int*)take((size_t)NE * 4);
    size_t zero_bytes = o;  // deg_v + cnt_e must be zeroed
    int* off_e = (int*)take((size_t)(NE + 1) * 4);
    int* cur_e = (int*)take((size_t)NE * 4);
    int* off_v = (int*)take((size_t)(NV + 1) * 4);
    int* cur_v = (int*)take((size_t)NV * 4);
    int* part = (int*)take(128 * 4);
    int* e_src = (int*)take((size_t)nnz * 4);
    int* v_edge = (int*)take((size_t)nnz * 4);
    float* beta = (float*)take((size_t)NE * 4);
    bf16* S = (bf16*)take((size_t)NE * DD * 2);
    bf16* Y = (bf16*)take((size_t)NE * DD * 2);
    bf16* Wb = (bf16*)take((size_t)DD * DD * 2);
    (void)ws_size; (void)n_in; (void)out_size;

    hipMemsetAsync(d_ws, 0, zero_bytes, stream);

    count_kernel<<<(nnz + 255) / 256, 256, 0, stream>>>(src, dst, deg_v, cnt_e, nnz);
    cvt_w<<<(DD * DD + 255) / 256, 256, 0, stream>>>(W, Wb, DD * DD);

    // exclusive scan cnt_e -> off_e / cur_e
    int nb_e = (NE + 1023) / 1024;
    scan_reduce<<<nb_e, 1024, 0, stream>>>(cnt_e, part, NE);
    scan_top<<<1, 128, 0, stream>>>(part, nb_e);
    scan_write<<<nb_e, 1024, 0, stream>>>(cnt_e, part, off_e, cur_e, NE);
    fill_e<<<(nnz + 255) / 256, 256, 0, stream>>>(src, dst, cur_e, e_src, nnz);

    // exclusive scan deg_v -> off_v / cur_v
    int nb_v = (NV + 1023) / 1024;
    scan_reduce<<<nb_v, 1024, 0, stream>>>(deg_v, part, NV);
    scan_top<<<1, 128, 0, stream>>>(part, nb_v);
    scan_write<<<nb_v, 1024, 0, stream>>>(deg_v, part, off_v, cur_v, NV);
    fill_v<<<(nnz + 255) / 256, 256, 0, stream>>>(src, dst, cur_v, v_edge, nnz);

    edge_agg<<<NE * 64 / 256, 256, 0, stream>>>(X, off_e, e_src, deg_v, S, beta);
    gemm_edge<<<((NE / 16) * 64 + 255) / 256, 256, 0, stream>>>(S, Wb, b, beta, Y);
    vertex_agg<<<NV * 64 / 256, 256, 0, stream>>>(Y, off_v, v_edge, (float*)d_out);
}

// Round 3
// 659.736 us; speedup vs baseline: 1.2188x; 1.2188x over previous
//
#include <hip/hip_runtime.h>
#include <hip/hip_bf16.h>

#define NV 100000
#define NE 20000
#define DD 128

using bf16 = __hip_bfloat16;
using bf16x2 = __hip_bfloat162;

typedef __attribute__((ext_vector_type(8))) short frag_ab;   // 8 bf16 in 4 VGPRs
typedef __attribute__((ext_vector_type(4))) float frag_cd;   // 4 fp32 acc

__device__ __forceinline__ float b2f(bf16 h) { return __bfloat162float(h); }

// ---------------- counting ----------------
__global__ void count_kernel(const int* __restrict__ src, const int* __restrict__ dst,
                             int* __restrict__ deg_v, int* __restrict__ cnt_e, int nnz) {
    int i = blockIdx.x * 256 + threadIdx.x;
    if (i < nnz) {
        atomicAdd(&deg_v[src[i]], 1);
        atomicAdd(&cnt_e[dst[i]], 1);
    }
}

// ---------------- fp32 -> bf16 conversions ----------------
__global__ void cvt_x(const float4* __restrict__ in, ushort4* __restrict__ out, int n4) {
    int i = blockIdx.x * 256 + threadIdx.x;
    if (i < n4) {
        float4 v = in[i];
        ushort4 o;
        bf16 a = __float2bfloat16(v.x); o.x = *(ushort*)&a;
        bf16 b = __float2bfloat16(v.y); o.y = *(ushort*)&b;
        bf16 c = __float2bfloat16(v.z); o.z = *(ushort*)&c;
        bf16 d = __float2bfloat16(v.w); o.w = *(ushort*)&d;
        out[i] = o;
    }
}

// ---------------- 3-kernel exclusive scan (n <= 128*1024) ----------------
__global__ void scan_reduce(const int* __restrict__ in, int* __restrict__ part, int n) {
    __shared__ int sm[1024];
    int t = threadIdx.x;
    int i = blockIdx.x * 1024 + t;
    sm[t] = (i < n) ? in[i] : 0;
    __syncthreads();
    for (int ofs = 512; ofs > 0; ofs >>= 1) {
        if (t < ofs) sm[t] += sm[t + ofs];
        __syncthreads();
    }
    if (t == 0) part[blockIdx.x] = sm[0];
}

__global__ void scan_top(int* part, int nb) {
    __shared__ int sm[128];
    int t = threadIdx.x;  // 128 threads
    int v = (t < nb) ? part[t] : 0;
    sm[t] = v;
    __syncthreads();
    for (int ofs = 1; ofs < 128; ofs <<= 1) {
        int x = (t >= ofs) ? sm[t - ofs] : 0;
        __syncthreads();
        sm[t] += x;
        __syncthreads();
    }
    if (t < nb) part[t] = sm[t] - v;  // exclusive
}

__global__ void scan_write(const int* __restrict__ in, const int* __restrict__ part,
                           int* __restrict__ off, int* __restrict__ cur, int n) {
    __shared__ int sm[1024];
    int t = threadIdx.x;
    int i = blockIdx.x * 1024 + t;
    int v = (i < n) ? in[i] : 0;
    sm[t] = v;
    __syncthreads();
    for (int ofs = 1; ofs < 1024; ofs <<= 1) {
        int x = (t >= ofs) ? sm[t - ofs] : 0;
        __syncthreads();
        sm[t] += x;
        __syncthreads();
    }
    int incl = sm[t];
    int base = part[blockIdx.x];
    if (i < n) {
        int ex = base + incl - v;
        off[i] = ex;
        cur[i] = ex;
        if (i == n - 1) off[n] = base + incl;
    }
}

// ---------------- fused CSR fill (counting sort, both directions) ----------------
__global__ void fill_both(const int* __restrict__ src, const int* __restrict__ dst,
                          int* __restrict__ cur_e, int* __restrict__ cur_v,
                          int* __restrict__ e_src, int* __restrict__ v_edge, int nnz) {
    int i = blockIdx.x * 256 + threadIdx.x;
    if (i < nnz) {
        int s = src[i], d = dst[i];
        int p = atomicAdd(&cur_e[d], 1);
        e_src[p] = s;
        int q = atomicAdd(&cur_v[s], 1);
        v_edge[q] = d;
    }
}

// ---------------- edge aggregation: S[e] = (De/cnt) * sum_{src in e} X[src] ----------------
// one wave per edge, lane covers 2 dims (bf16x2); manual unroll x8 for MLP
__global__ void edge_agg(const bf16* __restrict__ Xb, const int* __restrict__ off_e,
                         const int* __restrict__ e_src, const int* __restrict__ deg_v,
                         bf16* __restrict__ S, float* __restrict__ beta) {
    int wave = (blockIdx.x * blockDim.x + threadIdx.x) >> 6;
    int lane = threadIdx.x & 63;
    if (wave >= NE) return;
    int start = off_e[wave], end = off_e[wave + 1];
    float ax = 0.f, ay = 0.f;
    float degsum = 0.f;
    const bf16* Xl = Xb + lane * 2;
    int j = start;
    for (; j + 8 <= end; j += 8) {
        int s0 = e_src[j + 0], s1 = e_src[j + 1], s2 = e_src[j + 2], s3 = e_src[j + 3];
        int s4 = e_src[j + 4], s5 = e_src[j + 5], s6 = e_src[j + 6], s7 = e_src[j + 7];
        bf16x2 v0 = *(const bf16x2*)(Xl + (size_t)s0 * DD);
        bf16x2 v1 = *(const bf16x2*)(Xl + (size_t)s1 * DD);
        bf16x2 v2 = *(const bf16x2*)(Xl + (size_t)s2 * DD);
        bf16x2 v3 = *(const bf16x2*)(Xl + (size_t)s3 * DD);
        bf16x2 v4 = *(const bf16x2*)(Xl + (size_t)s4 * DD);
        bf16x2 v5 = *(const bf16x2*)(Xl + (size_t)s5 * DD);
        bf16x2 v6 = *(const bf16x2*)(Xl + (size_t)s6 * DD);
        bf16x2 v7 = *(const bf16x2*)(Xl + (size_t)s7 * DD);
        int d0 = deg_v[s0], d1 = deg_v[s1], d2 = deg_v[s2], d3 = deg_v[s3];
        int d4 = deg_v[s4], d5 = deg_v[s5], d6 = deg_v[s6], d7 = deg_v[s7];
        ax += b2f(v0.x) + b2f(v1.x) + b2f(v2.x) + b2f(v3.x)
            + b2f(v4.x) + b2f(v5.x) + b2f(v6.x) + b2f(v7.x);
        ay += b2f(v0.y) + b2f(v1.y) + b2f(v2.y) + b2f(v3.y)
            + b2f(v4.y) + b2f(v5.y) + b2f(v6.y) + b2f(v7.y);
        degsum += (float)(d0 + d1 + d2 + d3 + d4 + d5 + d6 + d7);
    }
    for (; j < end; ++j) {
        int s = e_src[j];
        bf16x2 v = *(const bf16x2*)(Xl + (size_t)s * DD);
        ax += b2f(v.x);
        ay += b2f(v.y);
        degsum += (float)deg_v[s];
    }
    float cntf = (float)(end - start);
    float Des = degsum / (cntf + 1.0f);
    float De = (Des > 0.f) ? rsqrtf(fmaxf(Des, 1e-30f)) : 1.0f;
    float scale = De / fmaxf(cntf, 1.0f);
    bf16x2 s2;
    s2.x = __float2bfloat16(ax * scale);
    s2.y = __float2bfloat16(ay * scale);
    *((bf16x2*)(S + (size_t)wave * DD + lane * 2)) = s2;
    if (lane == 0) beta[wave] = (cntf > 0.f) ? De : 0.f;  // coefficient for b
}

// ---------------- GEMM: Y = S @ W^T + beta * b  (MFMA 16x16x32 bf16) ----------------
__global__ __launch_bounds__(256) void gemm_edge(const bf16* __restrict__ S, const bf16* __restrict__ Wb,
                                                 const float* __restrict__ bias, const float* __restrict__ beta,
                                                 bf16* __restrict__ Y) {
    int wave = (blockIdx.x * blockDim.x + threadIdx.x) >> 6;
    int lane = threadIdx.x & 63;
    int mBase = wave * 16;
    if (mBase >= NE) return;
    int l16 = lane & 15, quad = lane >> 4;

    const short* Ss = (const short*)S;
    const short* Ws = (const short*)Wb;

    frag_ab a[4];
#pragma unroll
    for (int kt = 0; kt < 4; ++kt)
        a[kt] = *(const frag_ab*)(Ss + (size_t)(mBase + l16) * DD + kt * 32 + quad * 8);

    float beta_r[4];
#pragma unroll
    for (int r = 0; r < 4; ++r) beta_r[r] = beta[mBase + quad * 4 + r];

#pragma unroll
    for (int nt = 0; nt < 8; ++nt) {
        frag_cd acc = {0.f, 0.f, 0.f, 0.f};
#pragma unroll
        for (int kt = 0; kt < 4; ++kt) {
            frag_ab bfr = *(const frag_ab*)(Ws + (size_t)(nt * 16 + l16) * DD + kt * 32 + quad * 8);
            acc = __builtin_amdgcn_mfma_f32_16x16x32_bf16(a[kt], bfr, acc, 0, 0, 0);
        }
        float bv = bias[nt * 16 + l16];
#pragma unroll
        for (int r = 0; r < 4; ++r) {
            int row = mBase + quad * 4 + r;
            float v = acc[r] + beta_r[r] * bv;
            Y[(size_t)row * DD + nt * 16 + l16] = __float2bfloat16(v);
        }
    }
}

// ---------------- vertex aggregation + norm + relu (unroll x4) ----------------
__global__ void vertex_agg(const bf16* __restrict__ Y, const int* __restrict__ off_v,
                           const int* __restrict__ v_edge, float* __restrict__ out) {
    int wave = (blockIdx.x * blockDim.x + threadIdx.x) >> 6;
    int lane = threadIdx.x & 63;
    if (wave >= NV) return;
    int start = off_v[wave], end = off_v[wave + 1];
    float ax = 0.f, ay = 0.f;
    const bf16* Yl = Y + lane * 2;
    int j = start;
    for (; j + 4 <= end; j += 4) {
        int e0 = v_edge[j + 0], e1 = v_edge[j + 1], e2 = v_edge[j + 2], e3 = v_edge[j + 3];
        bf16x2 y0 = *(const bf16x2*)(Yl + (size_t)e0 * DD);
        bf16x2 y1 = *(const bf16x2*)(Yl + (size_t)e1 * DD);
        bf16x2 y2 = *(const bf16x2*)(Yl + (size_t)e2 * DD);
        bf16x2 y3 = *(const bf16x2*)(Yl + (size_t)e3 * DD);
        ax += b2f(y0.x) + b2f(y1.x) + b2f(y2.x) + b2f(y3.x);
        ay += b2f(y0.y) + b2f(y1.y) + b2f(y2.y) + b2f(y3.y);
    }
    for (; j < end; ++j) {
        int e = v_edge[j];
        bf16x2 y2 = *(const bf16x2*)(Yl + (size_t)e * DD);
        ax += b2f(y2.x);
        ay += b2f(y2.y);
    }
    int deg = end - start;
    float dvn = (deg > 0) ? rsqrtf((float)deg) : 0.f;
    float2 o;
    o.x = fmaxf(ax * dvn, 0.f);
    o.y = fmaxf(ay * dvn, 0.f);
    *((float2*)(out + (size_t)wave * DD + lane * 2)) = o;
}

extern "C" void kernel_launch(void* const* d_in, const int* in_sizes, int n_in,
                              void* d_out, int out_size, void* d_ws, size_t ws_size,
                              hipStream_t stream) {
    const float* X = (const float*)d_in[0];
    const float* W = (const float*)d_in[1];
    const float* b = (const float*)d_in[2];
    const int* src = (const int*)d_in[3];
    const int* dst = (const int*)d_in[4];
    int nnz = in_sizes[3];

    char* ws = (char*)d_ws;
    size_t o = 0;
    auto take = [&](size_t bytes) -> char* {
        char* p = ws + o;
        o += (bytes + 255) & ~(size_t)255;
        return p;
    };
    int* deg_v = (int*)take((size_t)NV * 4);
    int* cnt_e = (int*)take((size_t)NE * 4);
    size_t zero_bytes = o;  // deg_v + cnt_e must be zeroed
    int* off_e = (int*)take((size_t)(NE + 1) * 4);
    int* cur_e = (int*)take((size_t)NE * 4);
    int* off_v = (int*)take((size_t)(NV + 1) * 4);
    int* cur_v = (int*)take((size_t)NV * 4);
    int* part = (int*)take(128 * 4);
    int* e_src = (int*)take((size_t)nnz * 4);
    int* v_edge = (int*)take((size_t)nnz * 4);
    float* beta = (float*)take((size_t)NE * 4);
    bf16* S = (bf16*)take((size_t)NE * DD * 2);
    bf16* Y = (bf16*)take((size_t)NE * DD * 2);
    bf16* Wb = (bf16*)take((size_t)DD * DD * 2);
    bf16* Xb = (bf16*)take((size_t)NV * DD * 2);
    (void)ws_size; (void)n_in; (void)out_size;

    hipMemsetAsync(d_ws, 0, zero_bytes, stream);

    count_kernel<<<(nnz + 255) / 256, 256, 0, stream>>>(src, dst, deg_v, cnt_e, nnz);
    cvt_x<<<(NV * DD / 4 + 255) / 256, 256, 0, stream>>>((const float4*)X, (ushort4*)Xb, NV * DD / 4);
    cvt_x<<<(DD * DD / 4 + 255) / 256, 256, 0, stream>>>((const float4*)W, (ushort4*)Wb, DD * DD / 4);

    // exclusive scan cnt_e -> off_e / cur_e
    int nb_e = (NE + 1023) / 1024;
    scan_reduce<<<nb_e, 1024, 0, stream>>>(cnt_e, part, NE);
    scan_top<<<1, 128, 0, stream>>>(part, nb_e);
    scan_write<<<nb_e, 1024, 0, stream>>>(cnt_e, part, off_e, cur_e, NE);

    // exclusive scan deg_v -> off_v / cur_v
    int nb_v = (NV + 1023) / 1024;
    scan_reduce<<<nb_v, 1024, 0, stream>>>(deg_v, part, NV);
    scan_top<<<1, 128, 0, stream>>>(part, nb_v);
    scan_write<<<nb_v, 1024, 0, stream>>>(deg_v, part, off_v, cur_v, NV);

    fill_both<<<(nnz + 255) / 256, 256, 0, stream>>>(src, dst, cur_e, cur_v, e_src, v_edge, nnz);

    edge_agg<<<NE * 64 / 256, 256, 0, stream>>>(Xb, off_e, e_src, deg_v, S, beta);
    gemm_edge<<<((NE / 16) * 64 + 255) / 256, 256, 0, stream>>>(S, Wb, b, beta, Y);
    vertex_agg<<<NV * 64 / 256, 256, 0, stream>>>(Y, off_v, v_edge, (float*)d_out);
}

// Round 4
// 558.185 us; speedup vs baseline: 1.4406x; 1.1819x over previous
//
#include <hip/hip_runtime.h>
#include <hip/hip_bf16.h>

#define NV 100000
#define NE 20000
#define DD 128
#define NBK 128      // bucket slots (e uses 79, v uses 98)
#define CHUNK 2048   // entries per partition/count block

using bf16 = __hip_bfloat16;
using bf16x2 = __hip_bfloat162;

typedef __attribute__((ext_vector_type(8))) short frag_ab;   // 8 bf16 in 4 VGPRs
typedef __attribute__((ext_vector_type(4))) float frag_cd;   // 4 fp32 acc

__device__ __forceinline__ float b2f(bf16 h) { return __bfloat162float(h); }

// ---------------- counting (deg/cnt + bucket histograms) ----------------
__global__ __launch_bounds__(256) void count_kernel(const int* __restrict__ src, const int* __restrict__ dst,
                                                    int* __restrict__ deg_v, int* __restrict__ cnt_e,
                                                    int* __restrict__ bcnt_e, int* __restrict__ bcnt_v, int nnz) {
    __shared__ int lbe[NBK], lbv[NBK];
    int t = threadIdx.x;
    if (t < NBK) { lbe[t] = 0; lbv[t] = 0; }
    __syncthreads();
    int base = blockIdx.x * CHUNK;
#pragma unroll
    for (int k = 0; k < 8; ++k) {
        int i = base + k * 256 + t;
        if (i < nnz) {
            int s = src[i], d = dst[i];
            atomicAdd(&deg_v[s], 1);
            atomicAdd(&cnt_e[d], 1);
            atomicAdd(&lbe[d >> 8], 1);
            atomicAdd(&lbv[s >> 10], 1);
        }
    }
    __syncthreads();
    if (t < NBK) {
        if (lbe[t]) atomicAdd(&bcnt_e[t], lbe[t]);
        if (lbv[t]) atomicAdd(&bcnt_v[t], lbv[t]);
    }
}

// ---------------- fp32 -> bf16 conversions ----------------
__global__ void cvt_x(const float4* __restrict__ in, ushort4* __restrict__ out, int n4) {
    int i = blockIdx.x * 256 + threadIdx.x;
    if (i < n4) {
        float4 v = in[i];
        ushort4 o;
        bf16 a = __float2bfloat16(v.x); o.x = *(ushort*)&a;
        bf16 b = __float2bfloat16(v.y); o.y = *(ushort*)&b;
        bf16 c = __float2bfloat16(v.z); o.z = *(ushort*)&c;
        bf16 d = __float2bfloat16(v.w); o.w = *(ushort*)&d;
        out[i] = o;
    }
}

// ---------------- 3-kernel exclusive scan (n <= 128*1024) ----------------
__global__ void scan_reduce(const int* __restrict__ in, int* __restrict__ part, int n) {
    __shared__ int sm[1024];
    int t = threadIdx.x;
    int i = blockIdx.x * 1024 + t;
    sm[t] = (i < n) ? in[i] : 0;
    __syncthreads();
    for (int ofs = 512; ofs > 0; ofs >>= 1) {
        if (t < ofs) sm[t] += sm[t + ofs];
        __syncthreads();
    }
    if (t == 0) part[blockIdx.x] = sm[0];
}

__global__ void scan_top(int* part, int nb) {
    __shared__ int sm[128];
    int t = threadIdx.x;  // 128 threads
    int v = (t < nb) ? part[t] : 0;
    sm[t] = v;
    __syncthreads();
    for (int ofs = 1; ofs < 128; ofs <<= 1) {
        int x = (t >= ofs) ? sm[t - ofs] : 0;
        __syncthreads();
        sm[t] += x;
        __syncthreads();
    }
    if (t < nb) part[t] = sm[t] - v;  // exclusive
}

__global__ void scan_write(const int* __restrict__ in, const int* __restrict__ part,
                           int* __restrict__ off, int* __restrict__ cur, int n) {
    __shared__ int sm[1024];
    int t = threadIdx.x;
    int i = blockIdx.x * 1024 + t;
    int v = (i < n) ? in[i] : 0;
    sm[t] = v;
    __syncthreads();
    for (int ofs = 1; ofs < 1024; ofs <<= 1) {
        int x = (t >= ofs) ? sm[t - ofs] : 0;
        __syncthreads();
        sm[t] += x;
        __syncthreads();
    }
    int incl = sm[t];
    int base = part[blockIdx.x];
    if (i < n) {
        int ex = base + incl - v;
        off[i] = ex;
        cur[i] = ex;
        if (i == n - 1) off[n] = base + incl;
    }
}

// ---------------- bucket scan (1 block, 128 threads) ----------------
__global__ void bucket_scan(const int* __restrict__ bcnt_e, const int* __restrict__ bcnt_v,
                            int* __restrict__ bbase_e, int* __restrict__ bcur_e,
                            int* __restrict__ bbase_v, int* __restrict__ bcur_v) {
    __shared__ int sc[NBK];
    int t = threadIdx.x;  // 128
    int v = bcnt_e[t];
    sc[t] = v;
    __syncthreads();
    for (int ofs = 1; ofs < NBK; ofs <<= 1) {
        int x = (t >= ofs) ? sc[t - ofs] : 0;
        __syncthreads();
        sc[t] += x;
        __syncthreads();
    }
    int ex = sc[t] - v;
    bbase_e[t] = ex;
    bcur_e[t] = ex;
    __syncthreads();
    v = bcnt_v[t];
    sc[t] = v;
    __syncthreads();
    for (int ofs = 1; ofs < NBK; ofs <<= 1) {
        int x = (t >= ofs) ? sc[t - ofs] : 0;
        __syncthreads();
        sc[t] += x;
        __syncthreads();
    }
    ex = sc[t] - v;
    bbase_v[t] = ex;
    bcur_v[t] = ex;
}

// ---------------- LDS-staged radix partition (both directions) ----------------
__global__ __launch_bounds__(256) void partition_kernel(const int* __restrict__ src, const int* __restrict__ dst,
                                                        int* __restrict__ bcur_e, int* __restrict__ bcur_v,
                                                        uint2* __restrict__ pairs_e, uint2* __restrict__ pairs_v,
                                                        int nnz) {
    __shared__ int cnt[NBK], sc[NBK], loff[NBK], gbase[NBK];
    __shared__ uint2 stage[CHUNK];
    int t = threadIdx.x;
    int base = blockIdx.x * CHUNK;
    int s[8], d[8], rk[8];
#pragma unroll
    for (int k = 0; k < 8; ++k) {
        int i = base + k * 256 + t;
        if (i < nnz) { s[k] = src[i]; d[k] = dst[i]; } else { s[k] = -1; d[k] = -1; }
    }

    // ---- phase E: bucket by dst>>8 ----
    if (t < NBK) cnt[t] = 0;
    __syncthreads();
#pragma unroll
    for (int k = 0; k < 8; ++k)
        if (d[k] >= 0) rk[k] = atomicAdd(&cnt[d[k] >> 8], 1);
    __syncthreads();
    if (t < NBK) sc[t] = cnt[t];
    __syncthreads();
    for (int ofs = 1; ofs < NBK; ofs <<= 1) {
        int x = 0;
        if (t < NBK && t >= ofs) x = sc[t - ofs];
        __syncthreads();
        if (t < NBK) sc[t] += x;
        __syncthreads();
    }
    if (t < NBK) {
        loff[t] = sc[t] - cnt[t];
        gbase[t] = (cnt[t] > 0) ? atomicAdd(&bcur_e[t], cnt[t]) : 0;
    }
    __syncthreads();
#pragma unroll
    for (int k = 0; k < 8; ++k)
        if (d[k] >= 0) {
            int b = d[k] >> 8;
            stage[loff[b] + rk[k]] = make_uint2((unsigned)s[k], (unsigned)d[k]);
        }
    __syncthreads();
    {
        int wid = t >> 6, ln = t & 63;
        for (int b = wid; b < NBK; b += 4) {
            int n = cnt[b], lo = loff[b], gb = gbase[b];
            for (int idx = ln; idx < n; idx += 64) pairs_e[gb + idx] = stage[lo + idx];
        }
    }
    __syncthreads();

    // ---- phase V: bucket by src>>10 ----
    if (t < NBK) cnt[t] = 0;
    __syncthreads();
#pragma unroll
    for (int k = 0; k < 8; ++k)
        if (s[k] >= 0) rk[k] = atomicAdd(&cnt[s[k] >> 10], 1);
    __syncthreads();
    if (t < NBK) sc[t] = cnt[t];
    __syncthreads();
    for (int ofs = 1; ofs < NBK; ofs <<= 1) {
        int x = 0;
        if (t < NBK && t >= ofs) x = sc[t - ofs];
        __syncthreads();
        if (t < NBK) sc[t] += x;
        __syncthreads();
    }
    if (t < NBK) {
        loff[t] = sc[t] - cnt[t];
        gbase[t] = (cnt[t] > 0) ? atomicAdd(&bcur_v[t], cnt[t]) : 0;
    }
    __syncthreads();
#pragma unroll
    for (int k = 0; k < 8; ++k)
        if (s[k] >= 0) {
            int b = s[k] >> 10;
            stage[loff[b] + rk[k]] = make_uint2((unsigned)s[k], (unsigned)d[k]);
        }
    __syncthreads();
    {
        int wid = t >> 6, ln = t & 63;
        for (int b = wid; b < NBK; b += 4) {
            int n = cnt[b], lo = loff[b], gb = gbase[b];
            for (int idx = ln; idx < n; idx += 64) pairs_v[gb + idx] = stage[lo + idx];
        }
    }
}

// ---------------- bucket-local scatter (final CSR fill) ----------------
__global__ __launch_bounds__(256) void scatter_e(const uint2* __restrict__ pairs, const int* __restrict__ bbase,
                                                 const int* __restrict__ bend, int* __restrict__ cur_e,
                                                 int* __restrict__ e_src) {
    int b = blockIdx.x >> 3, sub = blockIdx.x & 7;
    int lo = bbase[b], hi = bend[b];
    for (int i = lo + sub * 256 + (int)threadIdx.x; i < hi; i += 2048) {
        uint2 p = pairs[i];
        int pos = atomicAdd(&cur_e[p.y], 1);
        e_src[pos] = (int)p.x;
    }
}

__global__ __launch_bounds__(256) void scatter_v(const uint2* __restrict__ pairs, const int* __restrict__ bbase,
                                                 const int* __restrict__ bend, int* __restrict__ cur_v,
                                                 int* __restrict__ v_edge) {
    int b = blockIdx.x >> 3, sub = blockIdx.x & 7;
    int lo = bbase[b], hi = bend[b];
    for (int i = lo + sub * 256 + (int)threadIdx.x; i < hi; i += 2048) {
        uint2 p = pairs[i];
        int pos = atomicAdd(&cur_v[p.x], 1);
        v_edge[pos] = (int)p.y;
    }
}

// ---------------- edge aggregation: S[e] = (De/cnt) * sum_{src in e} X[src] ----------------
__global__ void edge_agg(const bf16* __restrict__ Xb, const int* __restrict__ off_e,
                         const int* __restrict__ e_src, const int* __restrict__ deg_v,
                         bf16* __restrict__ S, float* __restrict__ beta) {
    int wave = (blockIdx.x * blockDim.x + threadIdx.x) >> 6;
    int lane = threadIdx.x & 63;
    if (wave >= NE) return;
    int start = off_e[wave], end = off_e[wave + 1];
    float ax = 0.f, ay = 0.f;
    float degsum = 0.f;
    const bf16* Xl = Xb + lane * 2;
    int j = start;
    for (; j + 8 <= end; j += 8) {
        int s0 = e_src[j + 0], s1 = e_src[j + 1], s2 = e_src[j + 2], s3 = e_src[j + 3];
        int s4 = e_src[j + 4], s5 = e_src[j + 5], s6 = e_src[j + 6], s7 = e_src[j + 7];
        bf16x2 v0 = *(const bf16x2*)(Xl + (size_t)s0 * DD);
        bf16x2 v1 = *(const bf16x2*)(Xl + (size_t)s1 * DD);
        bf16x2 v2 = *(const bf16x2*)(Xl + (size_t)s2 * DD);
        bf16x2 v3 = *(const bf16x2*)(Xl + (size_t)s3 * DD);
        bf16x2 v4 = *(const bf16x2*)(Xl + (size_t)s4 * DD);
        bf16x2 v5 = *(const bf16x2*)(Xl + (size_t)s5 * DD);
        bf16x2 v6 = *(const bf16x2*)(Xl + (size_t)s6 * DD);
        bf16x2 v7 = *(const bf16x2*)(Xl + (size_t)s7 * DD);
        int d0 = deg_v[s0], d1 = deg_v[s1], d2 = deg_v[s2], d3 = deg_v[s3];
        int d4 = deg_v[s4], d5 = deg_v[s5], d6 = deg_v[s6], d7 = deg_v[s7];
        ax += b2f(v0.x) + b2f(v1.x) + b2f(v2.x) + b2f(v3.x)
            + b2f(v4.x) + b2f(v5.x) + b2f(v6.x) + b2f(v7.x);
        ay += b2f(v0.y) + b2f(v1.y) + b2f(v2.y) + b2f(v3.y)
            + b2f(v4.y) + b2f(v5.y) + b2f(v6.y) + b2f(v7.y);
        degsum += (float)(d0 + d1 + d2 + d3 + d4 + d5 + d6 + d7);
    }
    for (; j < end; ++j) {
        int s = e_src[j];
        bf16x2 v = *(const bf16x2*)(Xl + (size_t)s * DD);
        ax += b2f(v.x);
        ay += b2f(v.y);
        degsum += (float)deg_v[s];
    }
    float cntf = (float)(end - start);
    float Des = degsum / (cntf + 1.0f);
    float De = (Des > 0.f) ? rsqrtf(fmaxf(Des, 1e-30f)) : 1.0f;
    float scale = De / fmaxf(cntf, 1.0f);
    bf16x2 s2;
    s2.x = __float2bfloat16(ax * scale);
    s2.y = __float2bfloat16(ay * scale);
    *((bf16x2*)(S + (size_t)wave * DD + lane * 2)) = s2;
    if (lane == 0) beta[wave] = (cntf > 0.f) ? De : 0.f;  // coefficient for b
}

// ---------------- GEMM: Y = S @ W^T + beta * b  (MFMA 16x16x32 bf16) ----------------
__global__ __launch_bounds__(256) void gemm_edge(const bf16* __restrict__ S, const bf16* __restrict__ Wb,
                                                 const float* __restrict__ bias, const float* __restrict__ beta,
                                                 bf16* __restrict__ Y) {
    int wave = (blockIdx.x * blockDim.x + threadIdx.x) >> 6;
    int lane = threadIdx.x & 63;
    int mBase = wave * 16;
    if (mBase >= NE) return;
    int l16 = lane & 15, quad = lane >> 4;

    const short* Ss = (const short*)S;
    const short* Ws = (const short*)Wb;

    frag_ab a[4];
#pragma unroll
    for (int kt = 0; kt < 4; ++kt)
        a[kt] = *(const frag_ab*)(Ss + (size_t)(mBase + l16) * DD + kt * 32 + quad * 8);

    float beta_r[4];
#pragma unroll
    for (int r = 0; r < 4; ++r) beta_r[r] = beta[mBase + quad * 4 + r];

#pragma unroll
    for (int nt = 0; nt < 8; ++nt) {
        frag_cd acc = {0.f, 0.f, 0.f, 0.f};
#pragma unroll
        for (int kt = 0; kt < 4; ++kt) {
            frag_ab bfr = *(const frag_ab*)(Ws + (size_t)(nt * 16 + l16) * DD + kt * 32 + quad * 8);
            acc = __builtin_amdgcn_mfma_f32_16x16x32_bf16(a[kt], bfr, acc, 0, 0, 0);
        }
        float bv = bias[nt * 16 + l16];
#pragma unroll
        for (int r = 0; r < 4; ++r) {
            int row = mBase + quad * 4 + r;
            float v = acc[r] + beta_r[r] * bv;
            Y[(size_t)row * DD + nt * 16 + l16] = __float2bfloat16(v);
        }
    }
}

// ---------------- vertex aggregation + norm + relu (unroll x8) ----------------
__global__ void vertex_agg(const bf16* __restrict__ Y, const int* __restrict__ off_v,
                           const int* __restrict__ v_edge, float* __restrict__ out) {
    int wave = (blockIdx.x * blockDim.x + threadIdx.x) >> 6;
    int lane = threadIdx.x & 63;
    if (wave >= NV) return;
    int start = off_v[wave], end = off_v[wave + 1];
    float ax = 0.f, ay = 0.f;
    const bf16* Yl = Y + lane * 2;
    int j = start;
    for (; j + 8 <= end; j += 8) {
        int e0 = v_edge[j + 0], e1 = v_edge[j + 1], e2 = v_edge[j + 2], e3 = v_edge[j + 3];
        int e4 = v_edge[j + 4], e5 = v_edge[j + 5], e6 = v_edge[j + 6], e7 = v_edge[j + 7];
        bf16x2 y0 = *(const bf16x2*)(Yl + (size_t)e0 * DD);
        bf16x2 y1 = *(const bf16x2*)(Yl + (size_t)e1 * DD);
        bf16x2 y2 = *(const bf16x2*)(Yl + (size_t)e2 * DD);
        bf16x2 y3 = *(const bf16x2*)(Yl + (size_t)e3 * DD);
        bf16x2 y4 = *(const bf16x2*)(Yl + (size_t)e4 * DD);
        bf16x2 y5 = *(const bf16x2*)(Yl + (size_t)e5 * DD);
        bf16x2 y6 = *(const bf16x2*)(Yl + (size_t)e6 * DD);
        bf16x2 y7 = *(const bf16x2*)(Yl + (size_t)e7 * DD);
        ax += b2f(y0.x) + b2f(y1.x) + b2f(y2.x) + b2f(y3.x)
            + b2f(y4.x) + b2f(y5.x) + b2f(y6.x) + b2f(y7.x);
        ay += b2f(y0.y) + b2f(y1.y) + b2f(y2.y) + b2f(y3.y)
            + b2f(y4.y) + b2f(y5.y) + b2f(y6.y) + b2f(y7.y);
    }
    for (; j < end; ++j) {
        int e = v_edge[j];
        bf16x2 y2 = *(const bf16x2*)(Yl + (size_t)e * DD);
        ax += b2f(y2.x);
        ay += b2f(y2.y);
    }
    int deg = end - start;
    float dvn = (deg > 0) ? rsqrtf((float)deg) : 0.f;
    float2 o;
    o.x = fmaxf(ax * dvn, 0.f);
    o.y = fmaxf(ay * dvn, 0.f);
    *((float2*)(out + (size_t)wave * DD + lane * 2)) = o;
}

extern "C" void kernel_launch(void* const* d_in, const int* in_sizes, int n_in,
                              void* d_out, int out_size, void* d_ws, size_t ws_size,
                              hipStream_t stream) {
    const float* X = (const float*)d_in[0];
    const float* W = (const float*)d_in[1];
    const float* b = (const float*)d_in[2];
    const int* src = (const int*)d_in[3];
    const int* dst = (const int*)d_in[4];
    int nnz = in_sizes[3];

    char* ws = (char*)d_ws;
    size_t o = 0;
    auto take = [&](size_t bytes) -> char* {
        char* p = ws + o;
        o += (bytes + 255) & ~(size_t)255;
        return p;
    };
    // zeroed region first
    int* deg_v = (int*)take((size_t)NV * 4);
    int* cnt_e = (int*)take((size_t)NE * 4);
    int* bcnt_e = (int*)take(NBK * 4);
    int* bcnt_v = (int*)take(NBK * 4);
    size_t zero_bytes = o;
    int* off_e = (int*)take((size_t)(NE + 1) * 4);
    int* cur_e = (int*)take((size_t)NE * 4);
    int* off_v = (int*)take((size_t)(NV + 1) * 4);
    int* cur_v = (int*)take((size_t)NV * 4);
    int* part = (int*)take(128 * 4);
    int* bbase_e = (int*)take(NBK * 4);
    int* bcur_e = (int*)take(NBK * 4);
    int* bbase_v = (int*)take(NBK * 4);
    int* bcur_v = (int*)take(NBK * 4);
    int* e_src = (int*)take((size_t)nnz * 4);
    int* v_edge = (int*)take((size_t)nnz * 4);
    uint2* pairs_e = (uint2*)take((size_t)nnz * 8);
    uint2* pairs_v = (uint2*)take((size_t)nnz * 8);
    float* beta = (float*)take((size_t)NE * 4);
    bf16* S = (bf16*)take((size_t)NE * DD * 2);
    bf16* Y = (bf16*)take((size_t)NE * DD * 2);
    bf16* Wb = (bf16*)take((size_t)DD * DD * 2);
    bf16* Xb = (bf16*)take((size_t)NV * DD * 2);
    (void)ws_size; (void)n_in; (void)out_size;

    hipMemsetAsync(d_ws, 0, zero_bytes, stream);

    int nchunk = (nnz + CHUNK - 1) / CHUNK;
    count_kernel<<<nchunk, 256, 0, stream>>>(src, dst, deg_v, cnt_e, bcnt_e, bcnt_v, nnz);
    cvt_x<<<(NV * DD / 4 + 255) / 256, 256, 0, stream>>>((const float4*)X, (ushort4*)Xb, NV * DD / 4);
    cvt_x<<<(DD * DD / 4 + 255) / 256, 256, 0, stream>>>((const float4*)W, (ushort4*)Wb, DD * DD / 4);

    // exclusive scan cnt_e -> off_e / cur_e
    int nb_e = (NE + 1023) / 1024;
    scan_reduce<<<nb_e, 1024, 0, stream>>>(cnt_e, part, NE);
    scan_top<<<1, 128, 0, stream>>>(part, nb_e);
    scan_write<<<nb_e, 1024, 0, stream>>>(cnt_e, part, off_e, cur_e, NE);

    // exclusive scan deg_v -> off_v / cur_v
    int nb_v = (NV + 1023) / 1024;
    scan_reduce<<<nb_v, 1024, 0, stream>>>(deg_v, part, NV);
    scan_top<<<1, 128, 0, stream>>>(part, nb_v);
    scan_write<<<nb_v, 1024, 0, stream>>>(deg_v, part, off_v, cur_v, NV);

    bucket_scan<<<1, 128, 0, stream>>>(bcnt_e, bcnt_v, bbase_e, bcur_e, bbase_v, bcur_v);
    partition_kernel<<<nchunk, 256, 0, stream>>>(src, dst, bcur_e, bcur_v, pairs_e, pairs_v, nnz);
    scatter_e<<<NBK * 8, 256, 0, stream>>>(pairs_e, bbase_e, bcur_e, cur_e, e_src);
    scatter_v<<<NBK * 8, 256, 0, stream>>>(pairs_v, bbase_v, bcur_v, cur_v, v_edge);

    edge_agg<<<NE * 64 / 256, 256, 0, stream>>>(Xb, off_e, e_src, deg_v, S, beta);
    gemm_edge<<<((NE / 16) * 64 + 255) / 256, 256, 0, stream>>>(S, Wb, b, beta, Y);
    vertex_agg<<<NV * 64 / 256, 256, 0, stream>>>(Y, off_v, v_edge, (float*)d_out);
}

// Round 5
// 326.123 us; speedup vs baseline: 2.4656x; 1.7116x over previous
//
#include <hip/hip_runtime.h>
#include <hip/hip_bf16.h>

#define NV 100000
#define NE 20000
#define DD 128
#define ESHIFT 7          // e-bucket = dst>>7  -> 157 buckets of 128 edges
#define VSHIFT 9          // v-bucket = src>>9  -> 196 buckets of 512 vertices
#define NBE 157
#define NBV 196
#define NBK 256           // bucket slots
#define CHUNK 4096        // entries per count/partition block (256 thr x 16)

using bf16 = __hip_bfloat16;
using bf16x2 = __hip_bfloat162;

typedef __attribute__((ext_vector_type(8))) short frag_ab;
typedef __attribute__((ext_vector_type(4))) float frag_cd;

__device__ __forceinline__ float b2f(bf16 h) { return __bfloat162float(h); }

// pack: p = (src<<15) | dst   (src<2^17, dst<2^15)
// ---------------- bucket counting (LDS only, 256 global atomics/block) ----------------
__global__ __launch_bounds__(256) void count_bucket(const int* __restrict__ src, const int* __restrict__ dst,
                                                    int* __restrict__ bcnt_e, int* __restrict__ bcnt_v, int nnz) {
    __shared__ int lbe[NBK], lbv[NBK];
    int t = threadIdx.x;
    lbe[t] = 0; lbv[t] = 0;
    __syncthreads();
    int base = blockIdx.x * CHUNK;
#pragma unroll
    for (int k = 0; k < 16; ++k) {
        int i = base + k * 256 + t;
        if (i < nnz) {
            atomicAdd(&lbe[dst[i] >> ESHIFT], 1);
            atomicAdd(&lbv[src[i] >> VSHIFT], 1);
        }
    }
    __syncthreads();
    if (lbe[t]) atomicAdd(&bcnt_e[t], lbe[t]);
    if (lbv[t]) atomicAdd(&bcnt_v[t], lbv[t]);
}

// ---------------- fp32 -> bf16 conversions ----------------
__global__ void cvt_x(const float4* __restrict__ in, ushort4* __restrict__ out, int n4) {
    int i = blockIdx.x * 256 + threadIdx.x;
    if (i < n4) {
        float4 v = in[i];
        ushort4 o;
        bf16 a = __float2bfloat16(v.x); o.x = *(ushort*)&a;
        bf16 b = __float2bfloat16(v.y); o.y = *(ushort*)&b;
        bf16 c = __float2bfloat16(v.z); o.z = *(ushort*)&c;
        bf16 d = __float2bfloat16(v.w); o.w = *(ushort*)&d;
        out[i] = o;
    }
}

// ---------------- bucket scan (1 block, 256 threads) ----------------
__global__ void bucket_scan(const int* __restrict__ bcnt_e, const int* __restrict__ bcnt_v,
                            int* __restrict__ bbase_e, int* __restrict__ bcur_e,
                            int* __restrict__ bbase_v, int* __restrict__ bcur_v) {
    __shared__ int sc[NBK];
    int t = threadIdx.x;
    int v = bcnt_e[t];
    sc[t] = v;
    __syncthreads();
    for (int o = 1; o < NBK; o <<= 1) { int x = (t >= o) ? sc[t - o] : 0; __syncthreads(); sc[t] += x; __syncthreads(); }
    int ex = sc[t] - v;
    bbase_e[t] = ex; bcur_e[t] = ex;
    __syncthreads();
    v = bcnt_v[t];
    sc[t] = v;
    __syncthreads();
    for (int o = 1; o < NBK; o <<= 1) { int x = (t >= o) ? sc[t - o] : 0; __syncthreads(); sc[t] += x; __syncthreads(); }
    ex = sc[t] - v;
    bbase_v[t] = ex; bcur_v[t] = ex;
}

// ---------------- LDS-staged radix partition into packed pairs ----------------
__global__ __launch_bounds__(256) void partition_kernel(const int* __restrict__ src, const int* __restrict__ dst,
                                                        int* __restrict__ bcur_e, int* __restrict__ bcur_v,
                                                        unsigned* __restrict__ pairs_e, unsigned* __restrict__ pairs_v,
                                                        int nnz) {
    __shared__ int cnt[NBK], sc[NBK], loff[NBK], gbase[NBK];
    __shared__ unsigned stage[CHUNK];
    int t = threadIdx.x;
    int base = blockIdx.x * CHUNK;
    unsigned p[16];
    int rk[16];
#pragma unroll
    for (int k = 0; k < 16; ++k) {
        int i = base + k * 256 + t;
        p[k] = (i < nnz) ? (((unsigned)src[i] << 15) | (unsigned)dst[i]) : 0xFFFFFFFFu;
    }

    // ---- phase E: bucket by dst>>7 = (p>>7)&0xff ----
    cnt[t] = 0;
    __syncthreads();
#pragma unroll
    for (int k = 0; k < 16; ++k)
        if (p[k] != 0xFFFFFFFFu) rk[k] = atomicAdd(&cnt[(p[k] >> ESHIFT) & 0x7FFu & 0xFF], 1);
    __syncthreads();
    sc[t] = cnt[t];
    __syncthreads();
    for (int o = 1; o < NBK; o <<= 1) { int x = (t >= o) ? sc[t - o] : 0; __syncthreads(); sc[t] += x; __syncthreads(); }
    loff[t] = sc[t] - cnt[t];
    gbase[t] = (cnt[t] > 0) ? atomicAdd(&bcur_e[t], cnt[t]) : 0;
    __syncthreads();
#pragma unroll
    for (int k = 0; k < 16; ++k)
        if (p[k] != 0xFFFFFFFFu) stage[loff[(p[k] >> ESHIFT) & 0xFF] + rk[k]] = p[k];
    __syncthreads();
    {
        int wid = t >> 6, ln = t & 63;
        for (int b2 = wid; b2 < NBK; b2 += 4) {
            int n = cnt[b2], lo = loff[b2], gb = gbase[b2];
            for (int idx = ln; idx < n; idx += 64) pairs_e[gb + idx] = stage[lo + idx];
        }
    }
    __syncthreads();

    // ---- phase V: bucket by src>>9 = p>>24 ----
    cnt[t] = 0;
    __syncthreads();
#pragma unroll
    for (int k = 0; k < 16; ++k)
        if (p[k] != 0xFFFFFFFFu) rk[k] = atomicAdd(&cnt[p[k] >> 24], 1);
    __syncthreads();
    sc[t] = cnt[t];
    __syncthreads();
    for (int o = 1; o < NBK; o <<= 1) { int x = (t >= o) ? sc[t - o] : 0; __syncthreads(); sc[t] += x; __syncthreads(); }
    loff[t] = sc[t] - cnt[t];
    gbase[t] = (cnt[t] > 0) ? atomicAdd(&bcur_v[t], cnt[t]) : 0;
    __syncthreads();
#pragma unroll
    for (int k = 0; k < 16; ++k)
        if (p[k] != 0xFFFFFFFFu) stage[loff[p[k] >> 24] + rk[k]] = p[k];
    __syncthreads();
    {
        int wid = t >> 6, ln = t & 63;
        for (int b2 = wid; b2 < NBK; b2 += 4) {
            int n = cnt[b2], lo = loff[b2], gb = gbase[b2];
            for (int idx = ln; idx < n; idx += 64) pairs_v[gb + idx] = stage[lo + idx];
        }
    }
}

// ---------------- fused per-bucket: histogram + scan + CSR fill (e side) ----------------
__global__ __launch_bounds__(1024) void build_e(const unsigned* __restrict__ pairs, const int* __restrict__ bbase,
                                                const int* __restrict__ bend,
                                                int* __restrict__ off_e, int* __restrict__ e_src) {
    __shared__ int cnt[128], sc2[128], cur[128];
    int b = blockIdx.x, t = threadIdx.x;
    int lo = bbase[b], hi = bend[b];
    if (t < 128) cnt[t] = 0;
    __syncthreads();
    for (int i = lo + t; i < hi; i += 1024) atomicAdd(&cnt[pairs[i] & 127], 1);
    __syncthreads();
    if (t < 128) sc2[t] = cnt[t];
    __syncthreads();
    for (int o = 1; o < 128; o <<= 1) {
        int x = 0;
        if (t < 128 && t >= o) x = sc2[t - o];
        __syncthreads();
        if (t < 128) sc2[t] += x;
        __syncthreads();
    }
    if (t < 128) {
        int ex = sc2[t] - cnt[t];
        cur[t] = ex;
        int e = (b << ESHIFT) + t;
        if (e < NE) off_e[e] = lo + ex;
    }
    if (t == 0 && b == NBE - 1) off_e[NE] = hi;
    __syncthreads();
    for (int i = lo + t; i < hi; i += 1024) {
        unsigned p = pairs[i];
        int r = atomicAdd(&cur[p & 127], 1);
        e_src[lo + r] = (int)(p >> 15);
    }
}

// ---------------- fused per-bucket: histogram + scan + CSR fill + deg_v (v side) ----------------
__global__ __launch_bounds__(1024) void build_v(const unsigned* __restrict__ pairs, const int* __restrict__ bbase,
                                                const int* __restrict__ bend,
                                                int* __restrict__ off_v, int* __restrict__ v_edge,
                                                int* __restrict__ deg_v) {
    __shared__ int cnt[512], sc2[512], cur[512];
    int b = blockIdx.x, t = threadIdx.x;
    int lo = bbase[b], hi = bend[b];
    if (t < 512) cnt[t] = 0;
    __syncthreads();
    for (int i = lo + t; i < hi; i += 1024) atomicAdd(&cnt[(pairs[i] >> 15) & 511], 1);
    __syncthreads();
    if (t < 512) sc2[t] = cnt[t];
    __syncthreads();
    for (int o = 1; o < 512; o <<= 1) {
        int x = 0;
        if (t < 512 && t >= o) x = sc2[t - o];
        __syncthreads();
        if (t < 512) sc2[t] += x;
        __syncthreads();
    }
    if (t < 512) {
        int ex = sc2[t] - cnt[t];
        cur[t] = ex;
        int v = (b << VSHIFT) + t;
        if (v < NV) { off_v[v] = lo + ex; deg_v[v] = cnt[t]; }
    }
    if (t == 0 && b == NBV - 1) off_v[NV] = hi;
    __syncthreads();
    for (int i = lo + t; i < hi; i += 1024) {
        unsigned p = pairs[i];
        int r = atomicAdd(&cur[(p >> 15) & 511], 1);
        v_edge[lo + r] = (int)(p & 0x7FFF);
    }
}

// ---------------- edge aggregation: S[e] = (De/cnt) * sum_{src in e} X[src] ----------------
__global__ void edge_agg(const bf16* __restrict__ Xb, const int* __restrict__ off_e,
                         const int* __restrict__ e_src, const int* __restrict__ deg_v,
                         bf16* __restrict__ S, float* __restrict__ beta) {
    int wave = (blockIdx.x * blockDim.x + threadIdx.x) >> 6;
    int lane = threadIdx.x & 63;
    if (wave >= NE) return;
    int start = off_e[wave], end = off_e[wave + 1];
    float ax = 0.f, ay = 0.f;
    float degsum = 0.f;
    const bf16* Xl = Xb + lane * 2;
    int j = start;
    for (; j + 8 <= end; j += 8) {
        int s0 = e_src[j + 0], s1 = e_src[j + 1], s2 = e_src[j + 2], s3 = e_src[j + 3];
        int s4 = e_src[j + 4], s5 = e_src[j + 5], s6 = e_src[j + 6], s7 = e_src[j + 7];
        bf16x2 v0 = *(const bf16x2*)(Xl + (size_t)s0 * DD);
        bf16x2 v1 = *(const bf16x2*)(Xl + (size_t)s1 * DD);
        bf16x2 v2 = *(const bf16x2*)(Xl + (size_t)s2 * DD);
        bf16x2 v3 = *(const bf16x2*)(Xl + (size_t)s3 * DD);
        bf16x2 v4 = *(const bf16x2*)(Xl + (size_t)s4 * DD);
        bf16x2 v5 = *(const bf16x2*)(Xl + (size_t)s5 * DD);
        bf16x2 v6 = *(const bf16x2*)(Xl + (size_t)s6 * DD);
        bf16x2 v7 = *(const bf16x2*)(Xl + (size_t)s7 * DD);
        int d0 = deg_v[s0], d1 = deg_v[s1], d2 = deg_v[s2], d3 = deg_v[s3];
        int d4 = deg_v[s4], d5 = deg_v[s5], d6 = deg_v[s6], d7 = deg_v[s7];
        ax += b2f(v0.x) + b2f(v1.x) + b2f(v2.x) + b2f(v3.x)
            + b2f(v4.x) + b2f(v5.x) + b2f(v6.x) + b2f(v7.x);
        ay += b2f(v0.y) + b2f(v1.y) + b2f(v2.y) + b2f(v3.y)
            + b2f(v4.y) + b2f(v5.y) + b2f(v6.y) + b2f(v7.y);
        degsum += (float)(d0 + d1 + d2 + d3 + d4 + d5 + d6 + d7);
    }
    for (; j < end; ++j) {
        int s = e_src[j];
        bf16x2 v = *(const bf16x2*)(Xl + (size_t)s * DD);
        ax += b2f(v.x);
        ay += b2f(v.y);
        degsum += (float)deg_v[s];
    }
    float cntf = (float)(end - start);
    float Des = degsum / (cntf + 1.0f);
    float De = (Des > 0.f) ? rsqrtf(fmaxf(Des, 1e-30f)) : 1.0f;
    float scale = De / fmaxf(cntf, 1.0f);
    bf16x2 s2;
    s2.x = __float2bfloat16(ax * scale);
    s2.y = __float2bfloat16(ay * scale);
    *((bf16x2*)(S + (size_t)wave * DD + lane * 2)) = s2;
    if (lane == 0) beta[wave] = (cntf > 0.f) ? De : 0.f;
}

// ---------------- GEMM: Y = S @ W^T + beta * b  (MFMA 16x16x32 bf16) ----------------
__global__ __launch_bounds__(256) void gemm_edge(const bf16* __restrict__ S, const bf16* __restrict__ Wb,
                                                 const float* __restrict__ bias, const float* __restrict__ beta,
                                                 bf16* __restrict__ Y) {
    int wave = (blockIdx.x * blockDim.x + threadIdx.x) >> 6;
    int lane = threadIdx.x & 63;
    int mBase = wave * 16;
    if (mBase >= NE) return;
    int l16 = lane & 15, quad = lane >> 4;

    const short* Ss = (const short*)S;
    const short* Ws = (const short*)Wb;

    frag_ab a[4];
#pragma unroll
    for (int kt = 0; kt < 4; ++kt)
        a[kt] = *(const frag_ab*)(Ss + (size_t)(mBase + l16) * DD + kt * 32 + quad * 8);

    float beta_r[4];
#pragma unroll
    for (int r = 0; r < 4; ++r) beta_r[r] = beta[mBase + quad * 4 + r];

#pragma unroll
    for (int nt = 0; nt < 8; ++nt) {
        frag_cd acc = {0.f, 0.f, 0.f, 0.f};
#pragma unroll
        for (int kt = 0; kt < 4; ++kt) {
            frag_ab bfr = *(const frag_ab*)(Ws + (size_t)(nt * 16 + l16) * DD + kt * 32 + quad * 8);
            acc = __builtin_amdgcn_mfma_f32_16x16x32_bf16(a[kt], bfr, acc, 0, 0, 0);
        }
        float bv = bias[nt * 16 + l16];
#pragma unroll
        for (int r = 0; r < 4; ++r) {
            int row = mBase + quad * 4 + r;
            float v = acc[r] + beta_r[r] * bv;
            Y[(size_t)row * DD + nt * 16 + l16] = __float2bfloat16(v);
        }
    }
}

// ---------------- vertex aggregation + norm + relu (unroll x8) ----------------
__global__ void vertex_agg(const bf16* __restrict__ Y, const int* __restrict__ off_v,
                           const int* __restrict__ v_edge, float* __restrict__ out) {
    int wave = (blockIdx.x * blockDim.x + threadIdx.x) >> 6;
    int lane = threadIdx.x & 63;
    if (wave >= NV) return;
    int start = off_v[wave], end = off_v[wave + 1];
    float ax = 0.f, ay = 0.f;
    const bf16* Yl = Y + lane * 2;
    int j = start;
    for (; j + 8 <= end; j += 8) {
        int e0 = v_edge[j + 0], e1 = v_edge[j + 1], e2 = v_edge[j + 2], e3 = v_edge[j + 3];
        int e4 = v_edge[j + 4], e5 = v_edge[j + 5], e6 = v_edge[j + 6], e7 = v_edge[j + 7];
        bf16x2 y0 = *(const bf16x2*)(Yl + (size_t)e0 * DD);
        bf16x2 y1 = *(const bf16x2*)(Yl + (size_t)e1 * DD);
        bf16x2 y2 = *(const bf16x2*)(Yl + (size_t)e2 * DD);
        bf16x2 y3 = *(const bf16x2*)(Yl + (size_t)e3 * DD);
        bf16x2 y4 = *(const bf16x2*)(Yl + (size_t)e4 * DD);
        bf16x2 y5 = *(const bf16x2*)(Yl + (size_t)e5 * DD);
        bf16x2 y6 = *(const bf16x2*)(Yl + (size_t)e6 * DD);
        bf16x2 y7 = *(const bf16x2*)(Yl + (size_t)e7 * DD);
        ax += b2f(y0.x) + b2f(y1.x) + b2f(y2.x) + b2f(y3.x)
            + b2f(y4.x) + b2f(y5.x) + b2f(y6.x) + b2f(y7.x);
        ay += b2f(y0.y) + b2f(y1.y) + b2f(y2.y) + b2f(y3.y)
            + b2f(y4.y) + b2f(y5.y) + b2f(y6.y) + b2f(y7.y);
    }
    for (; j < end; ++j) {
        int e = v_edge[j];
        bf16x2 y2 = *(const bf16x2*)(Yl + (size_t)e * DD);
        ax += b2f(y2.x);
        ay += b2f(y2.y);
    }
    int deg = end - start;
    float dvn = (deg > 0) ? rsqrtf((float)deg) : 0.f;
    float2 o;
    o.x = fmaxf(ax * dvn, 0.f);
    o.y = fmaxf(ay * dvn, 0.f);
    *((float2*)(out + (size_t)wave * DD + lane * 2)) = o;
}

extern "C" void kernel_launch(void* const* d_in, const int* in_sizes, int n_in,
                              void* d_out, int out_size, void* d_ws, size_t ws_size,
                              hipStream_t stream) {
    const float* X = (const float*)d_in[0];
    const float* W = (const float*)d_in[1];
    const float* b = (const float*)d_in[2];
    const int* src = (const int*)d_in[3];
    const int* dst = (const int*)d_in[4];
    int nnz = in_sizes[3];

    char* ws = (char*)d_ws;
    size_t o = 0;
    auto take = [&](size_t bytes) -> char* {
        char* p = ws + o;
        o += (bytes + 255) & ~(size_t)255;
        return p;
    };
    // zeroed region first
    int* bcnt_e = (int*)take(NBK * 4);
    int* bcnt_v = (int*)take(NBK * 4);
    size_t zero_bytes = o;
    int* bbase_e = (int*)take(NBK * 4);
    int* bcur_e = (int*)take(NBK * 4);
    int* bbase_v = (int*)take(NBK * 4);
    int* bcur_v = (int*)take(NBK * 4);
    int* off_e = (int*)take((size_t)(NE + 1) * 4);
    int* off_v = (int*)take((size_t)(NV + 1) * 4);
    int* deg_v = (int*)take((size_t)NV * 4);
    int* e_src = (int*)take((size_t)nnz * 4);
    int* v_edge = (int*)take((size_t)nnz * 4);
    unsigned* pairs_e = (unsigned*)take((size_t)nnz * 4);
    unsigned* pairs_v = (unsigned*)take((size_t)nnz * 4);
    float* beta = (float*)take((size_t)NE * 4);
    bf16* S = (bf16*)take((size_t)NE * DD * 2);
    bf16* Y = (bf16*)take((size_t)NE * DD * 2);
    bf16* Wb = (bf16*)take((size_t)DD * DD * 2);
    bf16* Xb = (bf16*)take((size_t)NV * DD * 2);
    (void)ws_size; (void)n_in; (void)out_size;

    hipMemsetAsync(d_ws, 0, zero_bytes, stream);

    int nchunk = (nnz + CHUNK - 1) / CHUNK;
    count_bucket<<<nchunk, 256, 0, stream>>>(src, dst, bcnt_e, bcnt_v, nnz);
    cvt_x<<<(NV * DD / 4 + 255) / 256, 256, 0, stream>>>((const float4*)X, (ushort4*)Xb, NV * DD / 4);
    cvt_x<<<(DD * DD / 4 + 255) / 256, 256, 0, stream>>>((const float4*)W, (ushort4*)Wb, DD * DD / 4);

    bucket_scan<<<1, NBK, 0, stream>>>(bcnt_e, bcnt_v, bbase_e, bcur_e, bbase_v, bcur_v);
    partition_kernel<<<nchunk, 256, 0, stream>>>(src, dst, bcur_e, bcur_v, pairs_e, pairs_v, nnz);
    build_e<<<NBE, 1024, 0, stream>>>(pairs_e, bbase_e, bcur_e, off_e, e_src);
    build_v<<<NBV, 1024, 0, stream>>>(pairs_v, bbase_v, bcur_v, off_v, v_edge, deg_v);

    edge_agg<<<NE * 64 / 256, 256, 0, stream>>>(Xb, off_e, e_src, deg_v, S, beta);
    gemm_edge<<<((NE / 16) * 64 + 255) / 256, 256, 0, stream>>>(S, Wb, b, beta, Y);
    vertex_agg<<<NV * 64 / 256, 256, 0, stream>>>(Y, off_v, v_edge, (float*)d_out);
}

// Round 6
// 307.772 us; speedup vs baseline: 2.6126x; 1.0596x over previous
//
#include <hip/hip_runtime.h>
#include <hip/hip_bf16.h>

#define NV 100000
#define NE 20000
#define DD 128
#define ESHIFT 7          // e-bucket = dst>>7  -> 157 buckets of 128 edges
#define VSHIFT 9          // v-bucket = src>>9  -> 196 buckets of 512 vertices
#define NBE 157
#define NBV 196
#define NBK 256           // bucket slots
#define CHUNK 4096        // entries per count/partition block (256 thr x 16)

using bf16 = __hip_bfloat16;
using bf16x2 = __hip_bfloat162;

typedef __attribute__((ext_vector_type(8))) short frag_ab;
typedef __attribute__((ext_vector_type(4))) float frag_cd;

__device__ __forceinline__ float us2f(unsigned short u) {
    union { unsigned u; float f; } c;
    c.u = ((unsigned)u) << 16;
    return c.f;
}

// ---------------- fused: bucket counting + fp32->bf16 conversion ----------------
__global__ __launch_bounds__(256) void count_and_cvt(const int* __restrict__ src, const int* __restrict__ dst,
                                                     int* __restrict__ bcnt_e, int* __restrict__ bcnt_v, int nnz,
                                                     const float4* __restrict__ Xf, ushort4* __restrict__ Xb,
                                                     const float4* __restrict__ Wf, ushort4* __restrict__ Wb) {
    __shared__ int lbe[NBK], lbv[NBK];
    int t = threadIdx.x;
    int nchunk = (nnz + CHUNK - 1) / CHUNK;
    if ((int)blockIdx.x < nchunk) {
        lbe[t] = 0; lbv[t] = 0;
        __syncthreads();
        int base = blockIdx.x * CHUNK;
#pragma unroll
        for (int k = 0; k < 16; ++k) {
            int i = base + k * 256 + t;
            if (i < nnz) {
                atomicAdd(&lbe[dst[i] >> ESHIFT], 1);
                atomicAdd(&lbv[src[i] >> VSHIFT], 1);
            }
        }
        __syncthreads();
        if (lbe[t]) atomicAdd(&bcnt_e[t], lbe[t]);
        if (lbv[t]) atomicAdd(&bcnt_v[t], lbv[t]);
    } else {
        const int n4x = NV * DD / 4;
        const int n4w = DD * DD / 4;
        int i = ((int)blockIdx.x - nchunk) * 256 + t;
        if (i < n4x + n4w) {
            float4 v;
            ushort4 o;
            if (i < n4x) v = Xf[i]; else v = Wf[i - n4x];
            bf16 a = __float2bfloat16(v.x); o.x = *(unsigned short*)&a;
            bf16 b = __float2bfloat16(v.y); o.y = *(unsigned short*)&b;
            bf16 c = __float2bfloat16(v.z); o.z = *(unsigned short*)&c;
            bf16 d = __float2bfloat16(v.w); o.w = *(unsigned short*)&d;
            if (i < n4x) Xb[i] = o; else Wb[i - n4x] = o;
        }
    }
}

// ---------------- bucket scan (1 block, 256 threads) ----------------
__global__ void bucket_scan(const int* __restrict__ bcnt_e, const int* __restrict__ bcnt_v,
                            int* __restrict__ bbase_e, int* __restrict__ bcur_e,
                            int* __restrict__ bbase_v, int* __restrict__ bcur_v) {
    __shared__ int sc[NBK];
    int t = threadIdx.x;
    int v = bcnt_e[t];
    sc[t] = v;
    __syncthreads();
    for (int o = 1; o < NBK; o <<= 1) { int x = (t >= o) ? sc[t - o] : 0; __syncthreads(); sc[t] += x; __syncthreads(); }
    int ex = sc[t] - v;
    bbase_e[t] = ex; bcur_e[t] = ex;
    __syncthreads();
    v = bcnt_v[t];
    sc[t] = v;
    __syncthreads();
    for (int o = 1; o < NBK; o <<= 1) { int x = (t >= o) ? sc[t - o] : 0; __syncthreads(); sc[t] += x; __syncthreads(); }
    ex = sc[t] - v;
    bbase_v[t] = ex; bcur_v[t] = ex;
}

// ---------------- LDS-staged radix partition into packed pairs ----------------
__global__ __launch_bounds__(256) void partition_kernel(const int* __restrict__ src, const int* __restrict__ dst,
                                                        int* __restrict__ bcur_e, int* __restrict__ bcur_v,
                                                        unsigned* __restrict__ pairs_e, unsigned* __restrict__ pairs_v,
                                                        int nnz) {
    __shared__ int cnt[NBK], sc[NBK], loff[NBK], gbase[NBK];
    __shared__ unsigned stage[CHUNK];
    int t = threadIdx.x;
    int base = blockIdx.x * CHUNK;
    unsigned p[16];
    int rk[16];
#pragma unroll
    for (int k = 0; k < 16; ++k) {
        int i = base + k * 256 + t;
        p[k] = (i < nnz) ? (((unsigned)src[i] << 15) | (unsigned)dst[i]) : 0xFFFFFFFFu;
    }

    // ---- phase E: bucket by dst>>7 ----
    cnt[t] = 0;
    __syncthreads();
#pragma unroll
    for (int k = 0; k < 16; ++k)
        if (p[k] != 0xFFFFFFFFu) rk[k] = atomicAdd(&cnt[(p[k] >> ESHIFT) & 0xFF], 1);
    __syncthreads();
    sc[t] = cnt[t];
    __syncthreads();
    for (int o = 1; o < NBK; o <<= 1) { int x = (t >= o) ? sc[t - o] : 0; __syncthreads(); sc[t] += x; __syncthreads(); }
    loff[t] = sc[t] - cnt[t];
    gbase[t] = (cnt[t] > 0) ? atomicAdd(&bcur_e[t], cnt[t]) : 0;
    __syncthreads();
#pragma unroll
    for (int k = 0; k < 16; ++k)
        if (p[k] != 0xFFFFFFFFu) stage[loff[(p[k] >> ESHIFT) & 0xFF] + rk[k]] = p[k];
    __syncthreads();
    {
        int wid = t >> 6, ln = t & 63;
        for (int b2 = wid; b2 < NBK; b2 += 4) {
            int n = cnt[b2], lo = loff[b2], gb = gbase[b2];
            for (int idx = ln; idx < n; idx += 64) pairs_e[gb + idx] = stage[lo + idx];
        }
    }
    __syncthreads();

    // ---- phase V: bucket by src>>9 ----
    cnt[t] = 0;
    __syncthreads();
#pragma unroll
    for (int k = 0; k < 16; ++k)
        if (p[k] != 0xFFFFFFFFu) rk[k] = atomicAdd(&cnt[p[k] >> 24], 1);
    __syncthreads();
    sc[t] = cnt[t];
    __syncthreads();
    for (int o = 1; o < NBK; o <<= 1) { int x = (t >= o) ? sc[t - o] : 0; __syncthreads(); sc[t] += x; __syncthreads(); }
    loff[t] = sc[t] - cnt[t];
    gbase[t] = (cnt[t] > 0) ? atomicAdd(&bcur_v[t], cnt[t]) : 0;
    __syncthreads();
#pragma unroll
    for (int k = 0; k < 16; ++k)
        if (p[k] != 0xFFFFFFFFu) stage[loff[p[k] >> 24] + rk[k]] = p[k];
    __syncthreads();
    {
        int wid = t >> 6, ln = t & 63;
        for (int b2 = wid; b2 < NBK; b2 += 4) {
            int n = cnt[b2], lo = loff[b2], gb = gbase[b2];
            for (int idx = ln; idx < n; idx += 64) pairs_v[gb + idx] = stage[lo + idx];
        }
    }
}

// ---------------- fused per-bucket CSR build (e side and v side in one grid) ----------------
__global__ __launch_bounds__(1024) void build_csr(const unsigned* __restrict__ pairs_e, const int* __restrict__ bbase_e,
                                                  const int* __restrict__ bend_e,
                                                  int* __restrict__ off_e, int* __restrict__ e_src,
                                                  const unsigned* __restrict__ pairs_v, const int* __restrict__ bbase_v,
                                                  const int* __restrict__ bend_v,
                                                  int* __restrict__ off_v, int* __restrict__ v_edge,
                                                  int* __restrict__ deg_v) {
    __shared__ int cnt[512], sc2[512], cur[512];
    int t = threadIdx.x;
    if ((int)blockIdx.x < NBE) {
        int b = blockIdx.x;
        int lo = bbase_e[b], hi = bend_e[b];
        if (t < 128) cnt[t] = 0;
        __syncthreads();
        for (int i = lo + t; i < hi; i += 1024) atomicAdd(&cnt[pairs_e[i] & 127], 1);
        __syncthreads();
        if (t < 128) sc2[t] = cnt[t];
        __syncthreads();
        for (int o = 1; o < 128; o <<= 1) {
            int x = 0;
            if (t < 128 && t >= o) x = sc2[t - o];
            __syncthreads();
            if (t < 128) sc2[t] += x;
            __syncthreads();
        }
        if (t < 128) {
            int ex = sc2[t] - cnt[t];
            cur[t] = ex;
            int e = (b << ESHIFT) + t;
            if (e < NE) off_e[e] = lo + ex;
        }
        if (t == 0 && b == NBE - 1) off_e[NE] = hi;
        __syncthreads();
        for (int i = lo + t; i < hi; i += 1024) {
            unsigned p = pairs_e[i];
            int r = atomicAdd(&cur[p & 127], 1);
            e_src[lo + r] = (int)(p >> 15);
        }
    } else {
        int b = blockIdx.x - NBE;
        int lo = bbase_v[b], hi = bend_v[b];
        if (t < 512) cnt[t] = 0;
        __syncthreads();
        for (int i = lo + t; i < hi; i += 1024) atomicAdd(&cnt[(pairs_v[i] >> 15) & 511], 1);
        __syncthreads();
        if (t < 512) sc2[t] = cnt[t];
        __syncthreads();
        for (int o = 1; o < 512; o <<= 1) {
            int x = 0;
            if (t < 512 && t >= o) x = sc2[t - o];
            __syncthreads();
            if (t < 512) sc2[t] += x;
            __syncthreads();
        }
        if (t < 512) {
            int ex = sc2[t] - cnt[t];
            cur[t] = ex;
            int v = (b << VSHIFT) + t;
            if (v < NV) { off_v[v] = lo + ex; deg_v[v] = cnt[t]; }
        }
        if (t == 0 && b == NBV - 1) off_v[NV] = hi;
        __syncthreads();
        for (int i = lo + t; i < hi; i += 1024) {
            unsigned p = pairs_v[i];
            int r = atomicAdd(&cur[(p >> 15) & 511], 1);
            v_edge[lo + r] = (int)(p & 0x7FFF);
        }
    }
}

// ---------------- edge aggregation: 2 members per wave-iteration, 8B loads ----------------
__global__ void edge_agg(const ushort4* __restrict__ Xb, const int* __restrict__ off_e,
                         const int* __restrict__ e_src, const int* __restrict__ deg_v,
                         bf16* __restrict__ S, float* __restrict__ beta) {
    int wave = (blockIdx.x * blockDim.x + threadIdx.x) >> 6;
    int lane = threadIdx.x & 63;
    if (wave >= NE) return;
    int half = lane >> 5, l32 = lane & 31;
    int start = off_e[wave], end = off_e[wave + 1];
    float a0 = 0.f, a1 = 0.f, a2 = 0.f, a3 = 0.f, degsum = 0.f;
    int j = start;
    for (; j + 16 <= end; j += 16) {
#pragma unroll
        for (int k = 0; k < 8; ++k) {
            int s = e_src[j + 2 * k + half];
            ushort4 x = Xb[(size_t)s * 32 + l32];
            int d = deg_v[s];
            a0 += us2f(x.x); a1 += us2f(x.y); a2 += us2f(x.z); a3 += us2f(x.w);
            degsum += (float)d;
        }
    }
    for (; j < end; j += 2) {
        int idx = j + half;
        if (idx < end) {
            int s = e_src[idx];
            ushort4 x = Xb[(size_t)s * 32 + l32];
            int d = deg_v[s];
            a0 += us2f(x.x); a1 += us2f(x.y); a2 += us2f(x.z); a3 += us2f(x.w);
            degsum += (float)d;
        }
    }
    // combine the two halves (same dims, different members)
    a0 += __shfl_xor(a0, 32);
    a1 += __shfl_xor(a1, 32);
    a2 += __shfl_xor(a2, 32);
    a3 += __shfl_xor(a3, 32);
    degsum += __shfl_xor(degsum, 32);

    float cntf = (float)(end - start);
    float Des = degsum / (cntf + 1.0f);
    float De = (Des > 0.f) ? rsqrtf(fmaxf(Des, 1e-30f)) : 1.0f;
    float scale = De / fmaxf(cntf, 1.0f);
    if (half == 0) {
        ushort4 o;
        bf16 b0 = __float2bfloat16(a0 * scale); o.x = *(unsigned short*)&b0;
        bf16 b1 = __float2bfloat16(a1 * scale); o.y = *(unsigned short*)&b1;
        bf16 b2 = __float2bfloat16(a2 * scale); o.z = *(unsigned short*)&b2;
        bf16 b3 = __float2bfloat16(a3 * scale); o.w = *(unsigned short*)&b3;
        ((ushort4*)S)[(size_t)wave * 32 + l32] = o;
        if (l32 == 0) beta[wave] = (cntf > 0.f) ? De : 0.f;
    }
}

// ---------------- GEMM: Y = S @ W^T + beta * b  (MFMA 16x16x32 bf16) ----------------
__global__ __launch_bounds__(256) void gemm_edge(const bf16* __restrict__ S, const bf16* __restrict__ Wb,
                                                 const float* __restrict__ bias, const float* __restrict__ beta,
                                                 bf16* __restrict__ Y) {
    int wave = (blockIdx.x * blockDim.x + threadIdx.x) >> 6;
    int lane = threadIdx.x & 63;
    int mBase = wave * 16;
    if (mBase >= NE) return;
    int l16 = lane & 15, quad = lane >> 4;

    const short* Ss = (const short*)S;
    const short* Ws = (const short*)Wb;

    frag_ab a[4];
#pragma unroll
    for (int kt = 0; kt < 4; ++kt)
        a[kt] = *(const frag_ab*)(Ss + (size_t)(mBase + l16) * DD + kt * 32 + quad * 8);

    float beta_r[4];
#pragma unroll
    for (int r = 0; r < 4; ++r) beta_r[r] = beta[mBase + quad * 4 + r];

#pragma unroll
    for (int nt = 0; nt < 8; ++nt) {
        frag_cd acc = {0.f, 0.f, 0.f, 0.f};
#pragma unroll
        for (int kt = 0; kt < 4; ++kt) {
            frag_ab bfr = *(const frag_ab*)(Ws + (size_t)(nt * 16 + l16) * DD + kt * 32 + quad * 8);
            acc = __builtin_amdgcn_mfma_f32_16x16x32_bf16(a[kt], bfr, acc, 0, 0, 0);
        }
        float bv = bias[nt * 16 + l16];
#pragma unroll
        for (int r = 0; r < 4; ++r) {
            int row = mBase + quad * 4 + r;
            float v = acc[r] + beta_r[r] * bv;
            Y[(size_t)row * DD + nt * 16 + l16] = __float2bfloat16(v);
        }
    }
}

// ---------------- vertex aggregation + norm + relu: 2 edges per wave-iteration ----------------
__global__ void vertex_agg(const ushort4* __restrict__ Y, const int* __restrict__ off_v,
                           const int* __restrict__ v_edge, float* __restrict__ out) {
    int wave = (blockIdx.x * blockDim.x + threadIdx.x) >> 6;
    int lane = threadIdx.x & 63;
    if (wave >= NV) return;
    int half = lane >> 5, l32 = lane & 31;
    int start = off_v[wave], end = off_v[wave + 1];
    float a0 = 0.f, a1 = 0.f, a2 = 0.f, a3 = 0.f;
    int j = start;
    for (; j + 8 <= end; j += 8) {
#pragma unroll
        for (int k = 0; k < 4; ++k) {
            int e = v_edge[j + 2 * k + half];
            ushort4 y = Y[(size_t)e * 32 + l32];
            a0 += us2f(y.x); a1 += us2f(y.y); a2 += us2f(y.z); a3 += us2f(y.w);
        }
    }
    for (; j < end; j += 2) {
        int idx = j + half;
        if (idx < end) {
            int e = v_edge[idx];
            ushort4 y = Y[(size_t)e * 32 + l32];
            a0 += us2f(y.x); a1 += us2f(y.y); a2 += us2f(y.z); a3 += us2f(y.w);
        }
    }
    a0 += __shfl_xor(a0, 32);
    a1 += __shfl_xor(a1, 32);
    a2 += __shfl_xor(a2, 32);
    a3 += __shfl_xor(a3, 32);
    int deg = end - start;
    float dvn = (deg > 0) ? rsqrtf((float)deg) : 0.f;
    if (half == 0) {
        float4 o;
        o.x = fmaxf(a0 * dvn, 0.f);
        o.y = fmaxf(a1 * dvn, 0.f);
        o.z = fmaxf(a2 * dvn, 0.f);
        o.w = fmaxf(a3 * dvn, 0.f);
        *((float4*)(out + (size_t)wave * DD + l32 * 4)) = o;
    }
}

extern "C" void kernel_launch(void* const* d_in, const int* in_sizes, int n_in,
                              void* d_out, int out_size, void* d_ws, size_t ws_size,
                              hipStream_t stream) {
    const float* X = (const float*)d_in[0];
    const float* W = (const float*)d_in[1];
    const float* b = (const float*)d_in[2];
    const int* src = (const int*)d_in[3];
    const int* dst = (const int*)d_in[4];
    int nnz = in_sizes[3];

    char* ws = (char*)d_ws;
    size_t o = 0;
    auto take = [&](size_t bytes) -> char* {
        char* p = ws + o;
        o += (bytes + 255) & ~(size_t)255;
        return p;
    };
    // zeroed region first
    int* bcnt_e = (int*)take(NBK * 4);
    int* bcnt_v = (int*)take(NBK * 4);
    size_t zero_bytes = o;
    int* bbase_e = (int*)take(NBK * 4);
    int* bcur_e = (int*)take(NBK * 4);
    int* bbase_v = (int*)take(NBK * 4);
    int* bcur_v = (int*)take(NBK * 4);
    int* off_e = (int*)take((size_t)(NE + 1) * 4);
    int* off_v = (int*)take((size_t)(NV + 1) * 4);
    int* deg_v = (int*)take((size_t)NV * 4);
    int* e_src = (int*)take((size_t)nnz * 4);
    int* v_edge = (int*)take((size_t)nnz * 4);
    unsigned* pairs_e = (unsigned*)take((size_t)nnz * 4);
    unsigned* pairs_v = (unsigned*)take((size_t)nnz * 4);
    float* beta = (float*)take((size_t)NE * 4);
    bf16* S = (bf16*)take((size_t)NE * DD * 2);
    bf16* Y = (bf16*)take((size_t)NE * DD * 2);
    bf16* Wb = (bf16*)take((size_t)DD * DD * 2);
    bf16* Xb = (bf16*)take((size_t)NV * DD * 2);
    (void)ws_size; (void)n_in; (void)out_size;

    hipMemsetAsync(d_ws, 0, zero_bytes, stream);

    int nchunk = (nnz + CHUNK - 1) / CHUNK;
    int ncvt = (NV * DD / 4 + DD * DD / 4 + 255) / 256;
    count_and_cvt<<<nchunk + ncvt, 256, 0, stream>>>(src, dst, bcnt_e, bcnt_v, nnz,
                                                     (const float4*)X, (ushort4*)Xb,
                                                     (const float4*)W, (ushort4*)Wb);
    bucket_scan<<<1, NBK, 0, stream>>>(bcnt_e, bcnt_v, bbase_e, bcur_e, bbase_v, bcur_v);
    partition_kernel<<<nchunk, 256, 0, stream>>>(src, dst, bcur_e, bcur_v, pairs_e, pairs_v, nnz);
    build_csr<<<NBE + NBV, 1024, 0, stream>>>(pairs_e, bbase_e, bcur_e, off_e, e_src,
                                              pairs_v, bbase_v, bcur_v, off_v, v_edge, deg_v);

    edge_agg<<<NE * 64 / 256, 256, 0, stream>>>((const ushort4*)Xb, off_e, e_src, deg_v, S, beta);
    gemm_edge<<<((NE / 16) * 64 + 255) / 256, 256, 0, stream>>>(S, Wb, b, beta, Y);
    vertex_agg<<<NV * 64 / 256, 256, 0, stream>>>((const ushort4*)Y, off_v, v_edge, (float*)d_out);
}

// Round 7
// 277.133 us; speedup vs baseline: 2.9015x; 1.1106x over previous
//
#include <hip/hip_runtime.h>
#include <hip/hip_bf16.h>

#define NV 100000
#define NE 20000
#define DD 128
#define ESHIFT 7          // e-bucket = dst>>7  -> 157 buckets
#define VSHIFT 9          // v-bucket = src>>9  -> 196 buckets
#define NBE 157
#define NBV 196
#define NBK 256
#define CHUNK 4096
#define CAPE 11264        // per-e-bucket capacity (mean 10240, sigma ~101)
#define CAPV 9216         // per-v-bucket capacity (mean 8192, sigma ~90)

using bf16 = __hip_bfloat16;

typedef __attribute__((ext_vector_type(8))) short frag_ab;
typedef __attribute__((ext_vector_type(4))) float frag_cd;

__device__ __forceinline__ float uas(unsigned u) { union { unsigned u; float f; } c; c.u = u; return c.f; }
__device__ __forceinline__ unsigned pk2(float lo, float hi) {
    bf16 l = __float2bfloat16(lo), h = __float2bfloat16(hi);
    return (unsigned)(*(unsigned short*)&l) | ((unsigned)(*(unsigned short*)&h) << 16);
}
__device__ __forceinline__ void accum8(float* a, uint4 x) {
    a[0] += uas(x.x << 16); a[1] += uas(x.x & 0xffff0000u);
    a[2] += uas(x.y << 16); a[3] += uas(x.y & 0xffff0000u);
    a[4] += uas(x.z << 16); a[5] += uas(x.z & 0xffff0000u);
    a[6] += uas(x.w << 16); a[7] += uas(x.w & 0xffff0000u);
}

// ---------------- init per-bucket cursors ----------------
__global__ void init_cur(int* __restrict__ bcur_e, int* __restrict__ bcur_v) {
    int t = threadIdx.x;  // 256
    bcur_e[t] = t * CAPE;
    bcur_v[t] = t * CAPV;
}

// ---------------- fused: LDS-staged radix partition + fp32->bf16 conversion ----------------
__global__ __launch_bounds__(256) void partition_and_cvt(const int* __restrict__ src, const int* __restrict__ dst,
                                                         int* __restrict__ bcur_e, int* __restrict__ bcur_v,
                                                         unsigned* __restrict__ pairs_e, unsigned* __restrict__ pairs_v,
                                                         int nnz,
                                                         const float4* __restrict__ Xf, ushort4* __restrict__ Xb,
                                                         const float4* __restrict__ Wf, ushort4* __restrict__ Wb) {
    int nchunk = (nnz + CHUNK - 1) / CHUNK;
    int t = threadIdx.x;
    if ((int)blockIdx.x >= nchunk) {
        const int n4x = NV * DD / 4;
        const int n4w = DD * DD / 4;
        int i = ((int)blockIdx.x - nchunk) * 256 + t;
        if (i < n4x + n4w) {
            float4 v;
            ushort4 o;
            if (i < n4x) v = Xf[i]; else v = Wf[i - n4x];
            bf16 a = __float2bfloat16(v.x); o.x = *(unsigned short*)&a;
            bf16 b = __float2bfloat16(v.y); o.y = *(unsigned short*)&b;
            bf16 c = __float2bfloat16(v.z); o.z = *(unsigned short*)&c;
            bf16 d = __float2bfloat16(v.w); o.w = *(unsigned short*)&d;
            if (i < n4x) Xb[i] = o; else Wb[i - n4x] = o;
        }
        return;
    }
    __shared__ int cnt[NBK], sc[NBK], loff[NBK], gbase[NBK];
    __shared__ unsigned stage[CHUNK];
    int base = blockIdx.x * CHUNK;
    unsigned p[16];
    int rk[16];
#pragma unroll
    for (int k = 0; k < 16; ++k) {
        int i = base + k * 256 + t;
        p[k] = (i < nnz) ? (((unsigned)src[i] << 15) | (unsigned)dst[i]) : 0xFFFFFFFFu;
    }

    // ---- phase E: bucket by dst>>7 ----
    cnt[t] = 0;
    __syncthreads();
#pragma unroll
    for (int k = 0; k < 16; ++k)
        if (p[k] != 0xFFFFFFFFu) rk[k] = atomicAdd(&cnt[(p[k] >> ESHIFT) & 0xFF], 1);
    __syncthreads();
    sc[t] = cnt[t];
    __syncthreads();
    for (int o = 1; o < NBK; o <<= 1) { int x = (t >= o) ? sc[t - o] : 0; __syncthreads(); sc[t] += x; __syncthreads(); }
    loff[t] = sc[t] - cnt[t];
    gbase[t] = (cnt[t] > 0) ? atomicAdd(&bcur_e[t], cnt[t]) : 0;
    __syncthreads();
#pragma unroll
    for (int k = 0; k < 16; ++k)
        if (p[k] != 0xFFFFFFFFu) stage[loff[(p[k] >> ESHIFT) & 0xFF] + rk[k]] = p[k];
    __syncthreads();
    {
        int wid = t >> 6, ln = t & 63;
        for (int b2 = wid; b2 < NBK; b2 += 4) {
            int n = cnt[b2], lo = loff[b2], gb = gbase[b2];
            for (int idx = ln; idx < n; idx += 64) pairs_e[gb + idx] = stage[lo + idx];
        }
    }
    __syncthreads();

    // ---- phase V: bucket by src>>9 ----
    cnt[t] = 0;
    __syncthreads();
#pragma unroll
    for (int k = 0; k < 16; ++k)
        if (p[k] != 0xFFFFFFFFu) rk[k] = atomicAdd(&cnt[p[k] >> 24], 1);
    __syncthreads();
    sc[t] = cnt[t];
    __syncthreads();
    for (int o = 1; o < NBK; o <<= 1) { int x = (t >= o) ? sc[t - o] : 0; __syncthreads(); sc[t] += x; __syncthreads(); }
    loff[t] = sc[t] - cnt[t];
    gbase[t] = (cnt[t] > 0) ? atomicAdd(&bcur_v[t], cnt[t]) : 0;
    __syncthreads();
#pragma unroll
    for (int k = 0; k < 16; ++k)
        if (p[k] != 0xFFFFFFFFu) stage[loff[p[k] >> 24] + rk[k]] = p[k];
    __syncthreads();
    {
        int wid = t >> 6, ln = t & 63;
        for (int b2 = wid; b2 < NBK; b2 += 4) {
            int n = cnt[b2], lo = loff[b2], gb = gbase[b2];
            for (int idx = ln; idx < n; idx += 64) pairs_v[gb + idx] = stage[lo + idx];
        }
    }
}

// ---------------- fused per-bucket CSR build (e side and v side in one grid) ----------------
__global__ __launch_bounds__(1024) void build_csr(const unsigned* __restrict__ pairs_e, const int* __restrict__ bcur_e,
                                                  int* __restrict__ off_e, int* __restrict__ end_e, int* __restrict__ e_src,
                                                  const unsigned* __restrict__ pairs_v, const int* __restrict__ bcur_v,
                                                  int* __restrict__ off_v, int* __restrict__ end_v, int* __restrict__ v_edge,
                                                  int* __restrict__ deg_v) {
    __shared__ int cnt[512], sc2[512], cur[512];
    int t = threadIdx.x;
    if ((int)blockIdx.x < NBE) {
        int b = blockIdx.x;
        int lo = b * CAPE, hi = bcur_e[b];
        if (t < 128) cnt[t] = 0;
        __syncthreads();
        for (int i = lo + t; i < hi; i += 1024) atomicAdd(&cnt[pairs_e[i] & 127], 1);
        __syncthreads();
        if (t < 128) sc2[t] = cnt[t];
        __syncthreads();
        for (int o = 1; o < 128; o <<= 1) {
            int x = 0;
            if (t < 128 && t >= o) x = sc2[t - o];
            __syncthreads();
            if (t < 128) sc2[t] += x;
            __syncthreads();
        }
        if (t < 128) {
            int ex = sc2[t] - cnt[t];
            cur[t] = ex;
            int e = (b << ESHIFT) + t;
            if (e < NE) { off_e[e] = lo + ex; end_e[e] = lo + ex + cnt[t]; }
        }
        __syncthreads();
        for (int i = lo + t; i < hi; i += 1024) {
            unsigned p = pairs_e[i];
            int r = atomicAdd(&cur[p & 127], 1);
            e_src[lo + r] = (int)(p >> 15);
        }
    } else {
        int b = blockIdx.x - NBE;
        int lo = b * CAPV, hi = bcur_v[b];
        if (t < 512) cnt[t] = 0;
        __syncthreads();
        for (int i = lo + t; i < hi; i += 1024) atomicAdd(&cnt[(pairs_v[i] >> 15) & 511], 1);
        __syncthreads();
        if (t < 512) sc2[t] = cnt[t];
        __syncthreads();
        for (int o = 1; o < 512; o <<= 1) {
            int x = 0;
            if (t < 512 && t >= o) x = sc2[t - o];
            __syncthreads();
            if (t < 512) sc2[t] += x;
            __syncthreads();
        }
        if (t < 512) {
            int ex = sc2[t] - cnt[t];
            cur[t] = ex;
            int v = (b << VSHIFT) + t;
            if (v < NV) { off_v[v] = lo + ex; end_v[v] = lo + ex + cnt[t]; deg_v[v] = cnt[t]; }
        }
        __syncthreads();
        for (int i = lo + t; i < hi; i += 1024) {
            unsigned p = pairs_v[i];
            int r = atomicAdd(&cur[(p >> 15) & 511], 1);
            v_edge[lo + r] = (int)(p & 0x7FFF);
        }
    }
}

// ---------------- edge aggregation: 4 members/instr, 16B row-slice loads ----------------
__global__ __launch_bounds__(256) void edge_agg(const uint4* __restrict__ Xq, const int* __restrict__ off_e,
                                                const int* __restrict__ end_e,
                                                const int* __restrict__ e_src, const int* __restrict__ deg_v,
                                                uint4* __restrict__ Sq, float* __restrict__ beta) {
    int wave = (blockIdx.x * blockDim.x + threadIdx.x) >> 6;
    int lane = threadIdx.x & 63;
    if (wave >= NE) return;
    int g = lane >> 4, l16 = lane & 15;
    int start = off_e[wave], end = end_e[wave];
    float acc[8] = {0.f, 0.f, 0.f, 0.f, 0.f, 0.f, 0.f, 0.f};
    float degsum = 0.f;
    int j = start;
    for (; j + 16 <= end; j += 16) {
        int s0 = e_src[j + g];
        int s1 = e_src[j + 4 + g];
        int s2 = e_src[j + 8 + g];
        int s3 = e_src[j + 12 + g];
        uint4 x0 = Xq[(size_t)s0 * 16 + l16];
        uint4 x1 = Xq[(size_t)s1 * 16 + l16];
        uint4 x2 = Xq[(size_t)s2 * 16 + l16];
        uint4 x3 = Xq[(size_t)s3 * 16 + l16];
        degsum += (float)(deg_v[s0] + deg_v[s1] + deg_v[s2] + deg_v[s3]);
        accum8(acc, x0);
        accum8(acc, x1);
        accum8(acc, x2);
        accum8(acc, x3);
    }
    for (; j < end; j += 4) {
        int idx = j + g;
        if (idx < end) {
            int s = e_src[idx];
            uint4 x = Xq[(size_t)s * 16 + l16];
            degsum += (float)deg_v[s];
            accum8(acc, x);
        }
    }
#pragma unroll
    for (int i = 0; i < 8; ++i) {
        acc[i] += __shfl_xor(acc[i], 16);
        acc[i] += __shfl_xor(acc[i], 32);
    }
    degsum += __shfl_xor(degsum, 16);
    degsum += __shfl_xor(degsum, 32);

    float cntf = (float)(end - start);
    float Des = degsum / (cntf + 1.0f);
    float De = (Des > 0.f) ? rsqrtf(fmaxf(Des, 1e-30f)) : 1.0f;
    float scale = De / fmaxf(cntf, 1.0f);
    if (g == 0) {
        uint4 o;
        o.x = pk2(acc[0] * scale, acc[1] * scale);
        o.y = pk2(acc[2] * scale, acc[3] * scale);
        o.z = pk2(acc[4] * scale, acc[5] * scale);
        o.w = pk2(acc[6] * scale, acc[7] * scale);
        Sq[(size_t)wave * 16 + l16] = o;
        if (l16 == 0) beta[wave] = (cntf > 0.f) ? De : 0.f;
    }
}

// ---------------- GEMM: Y = S @ W^T + beta * b  (MFMA 16x16x32 bf16) ----------------
__global__ __launch_bounds__(256) void gemm_edge(const bf16* __restrict__ S, const bf16* __restrict__ Wb,
                                                 const float* __restrict__ bias, const float* __restrict__ beta,
                                                 bf16* __restrict__ Y) {
    int wave = (blockIdx.x * blockDim.x + threadIdx.x) >> 6;
    int lane = threadIdx.x & 63;
    int mBase = wave * 16;
    if (mBase >= NE) return;
    int l16 = lane & 15, quad = lane >> 4;

    const short* Ss = (const short*)S;
    const short* Ws = (const short*)Wb;

    frag_ab a[4];
#pragma unroll
    for (int kt = 0; kt < 4; ++kt)
        a[kt] = *(const frag_ab*)(Ss + (size_t)(mBase + l16) * DD + kt * 32 + quad * 8);

    float beta_r[4];
#pragma unroll
    for (int r = 0; r < 4; ++r) beta_r[r] = beta[mBase + quad * 4 + r];

#pragma unroll
    for (int nt = 0; nt < 8; ++nt) {
        frag_cd acc = {0.f, 0.f, 0.f, 0.f};
#pragma unroll
        for (int kt = 0; kt < 4; ++kt) {
            frag_ab bfr = *(const frag_ab*)(Ws + (size_t)(nt * 16 + l16) * DD + kt * 32 + quad * 8);
            acc = __builtin_amdgcn_mfma_f32_16x16x32_bf16(a[kt], bfr, acc, 0, 0, 0);
        }
        float bv = bias[nt * 16 + l16];
#pragma unroll
        for (int r = 0; r < 4; ++r) {
            int row = mBase + quad * 4 + r;
            float v = acc[r] + beta_r[r] * bv;
            Y[(size_t)row * DD + nt * 16 + l16] = __float2bfloat16(v);
        }
    }
}

// ---------------- vertex aggregation + norm + relu: 16B row-slice loads ----------------
__global__ __launch_bounds__(256) void vertex_agg(const uint4* __restrict__ Yq, const int* __restrict__ off_v,
                                                  const int* __restrict__ end_v,
                                                  const int* __restrict__ v_edge, float* __restrict__ out) {
    int wave = (blockIdx.x * blockDim.x + threadIdx.x) >> 6;
    int lane = threadIdx.x & 63;
    if (wave >= NV) return;
    int g = lane >> 4, l16 = lane & 15;
    int start = off_v[wave], end = end_v[wave];
    float acc[8] = {0.f, 0.f, 0.f, 0.f, 0.f, 0.f, 0.f, 0.f};
    int j = start;
    for (; j + 8 <= end; j += 8) {
        int e0 = v_edge[j + g];
        int e1 = v_edge[j + 4 + g];
        uint4 y0 = Yq[(size_t)e0 * 16 + l16];
        uint4 y1 = Yq[(size_t)e1 * 16 + l16];
        accum8(acc, y0);
        accum8(acc, y1);
    }
    for (; j < end; j += 4) {
        int idx = j + g;
        if (idx < end) {
            int e = v_edge[idx];
            uint4 y = Yq[(size_t)e * 16 + l16];
            accum8(acc, y);
        }
    }
#pragma unroll
    for (int i = 0; i < 8; ++i) {
        acc[i] += __shfl_xor(acc[i], 16);
        acc[i] += __shfl_xor(acc[i], 32);
    }
    int deg = end - start;
    float dvn = (deg > 0) ? rsqrtf((float)deg) : 0.f;
    if (g == 0) {
        float4 o1, o2;
        o1.x = fmaxf(acc[0] * dvn, 0.f);
        o1.y = fmaxf(acc[1] * dvn, 0.f);
        o1.z = fmaxf(acc[2] * dvn, 0.f);
        o1.w = fmaxf(acc[3] * dvn, 0.f);
        o2.x = fmaxf(acc[4] * dvn, 0.f);
        o2.y = fmaxf(acc[5] * dvn, 0.f);
        o2.z = fmaxf(acc[6] * dvn, 0.f);
        o2.w = fmaxf(acc[7] * dvn, 0.f);
        float4* op = (float4*)(out + (size_t)wave * DD + l16 * 8);
        op[0] = o1;
        op[1] = o2;
    }
}

extern "C" void kernel_launch(void* const* d_in, const int* in_sizes, int n_in,
                              void* d_out, int out_size, void* d_ws, size_t ws_size,
                              hipStream_t stream) {
    const float* X = (const float*)d_in[0];
    const float* W = (const float*)d_in[1];
    const float* b = (const float*)d_in[2];
    const int* src = (const int*)d_in[3];
    const int* dst = (const int*)d_in[4];
    int nnz = in_sizes[3];

    char* ws = (char*)d_ws;
    size_t o = 0;
    auto take = [&](size_t bytes) -> char* {
        char* p = ws + o;
        o += (bytes + 255) & ~(size_t)255;
        return p;
    };
    int* bcur_e = (int*)take(NBK * 4);
    int* bcur_v = (int*)take(NBK * 4);
    int* off_e = (int*)take((size_t)NE * 4);
    int* end_e = (int*)take((size_t)NE * 4);
    int* off_v = (int*)take((size_t)NV * 4);
    int* end_v = (int*)take((size_t)NV * 4);
    int* deg_v = (int*)take((size_t)NV * 4);
    int* e_src = (int*)take((size_t)NBE * CAPE * 4);
    int* v_edge = (int*)take((size_t)NBV * CAPV * 4);
    unsigned* pairs_e = (unsigned*)take((size_t)NBE * CAPE * 4);
    unsigned* pairs_v = (unsigned*)take((size_t)NBV * CAPV * 4);
    float* beta = (float*)take((size_t)NE * 4);
    bf16* S = (bf16*)take((size_t)NE * DD * 2);
    bf16* Y = (bf16*)take((size_t)NE * DD * 2);
    bf16* Wb = (bf16*)take((size_t)DD * DD * 2);
    bf16* Xb = (bf16*)take((size_t)NV * DD * 2);
    (void)ws_size; (void)n_in; (void)out_size;

    int nchunk = (nnz + CHUNK - 1) / CHUNK;
    int ncvt = (NV * DD / 4 + DD * DD / 4 + 255) / 256;

    init_cur<<<1, NBK, 0, stream>>>(bcur_e, bcur_v);
    partition_and_cvt<<<nchunk + ncvt, 256, 0, stream>>>(src, dst, bcur_e, bcur_v, pairs_e, pairs_v, nnz,
                                                         (const float4*)X, (ushort4*)Xb,
                                                         (const float4*)W, (ushort4*)Wb);
    build_csr<<<NBE + NBV, 1024, 0, stream>>>(pairs_e, bcur_e, off_e, end_e, e_src,
                                              pairs_v, bcur_v, off_v, end_v, v_edge, deg_v);

    edge_agg<<<NE * 64 / 256, 256, 0, stream>>>((const uint4*)Xb, off_e, end_e, e_src, deg_v, (uint4*)S, beta);
    gemm_edge<<<(NE / 16 * 64 + 255) / 256, 256, 0, stream>>>(S, Wb, b, beta, Y);
    vertex_agg<<<NV * 64 / 256, 256, 0, stream>>>((const uint4*)Y, off_v, end_v, v_edge, (float*)d_out);
}

// Round 8
// 268.011 us; speedup vs baseline: 3.0002x; 1.0340x over previous
//
#include <hip/hip_runtime.h>
#include <hip/hip_bf16.h>

#define NV 100000
#define NE 20000
#define DD 128
#define ESHIFT 7          // e-bucket = dst>>7  -> 157 buckets
#define VSHIFT 9          // v-bucket = src>>9  -> 196 buckets
#define NBE 157
#define NBV 196
#define NBK 256
#define CHUNK 4096
#define CAPE 11264        // per-e-bucket capacity (mean 10240, sigma ~101)
#define CAPV 9216         // per-v-bucket capacity (mean 8192, sigma ~90)

using bf16 = __hip_bfloat16;

typedef __attribute__((ext_vector_type(8))) short frag_ab;
typedef __attribute__((ext_vector_type(4))) float frag_cd;

__device__ __forceinline__ float uas(unsigned u) { union { unsigned u; float f; } c; c.u = u; return c.f; }
__device__ __forceinline__ unsigned pk2(float lo, float hi) {
    bf16 l = __float2bfloat16(lo), h = __float2bfloat16(hi);
    return (unsigned)(*(unsigned short*)&l) | ((unsigned)(*(unsigned short*)&h) << 16);
}
__device__ __forceinline__ void accum8(float* a, uint4 x) {
    a[0] += uas(x.x << 16); a[1] += uas(x.x & 0xffff0000u);
    a[2] += uas(x.y << 16); a[3] += uas(x.y & 0xffff0000u);
    a[4] += uas(x.z << 16); a[5] += uas(x.z & 0xffff0000u);
    a[6] += uas(x.w << 16); a[7] += uas(x.w & 0xffff0000u);
}

// ---------------- init per-bucket cursors ----------------
__global__ void init_cur(int* __restrict__ bcur_e, int* __restrict__ bcur_v) {
    int t = threadIdx.x;  // 256
    bcur_e[t] = t * CAPE;
    bcur_v[t] = t * CAPV;
}

// ---------------- fused: LDS-staged radix partition (2-way split counters) + cvt ----------------
__global__ __launch_bounds__(256) void partition_and_cvt(const int* __restrict__ src, const int* __restrict__ dst,
                                                         int* __restrict__ bcur_e, int* __restrict__ bcur_v,
                                                         unsigned* __restrict__ pairs_e, unsigned* __restrict__ pairs_v,
                                                         int nnz,
                                                         const float4* __restrict__ Xf, ushort4* __restrict__ Xb,
                                                         const float4* __restrict__ Wf, ushort4* __restrict__ Wb) {
    int nchunk = (nnz + CHUNK - 1) / CHUNK;
    int t = threadIdx.x;
    if ((int)blockIdx.x >= nchunk) {
        const int n4x = NV * DD / 4;
        const int n4w = DD * DD / 4;
        int i = ((int)blockIdx.x - nchunk) * 256 + t;
        if (i < n4x + n4w) {
            float4 v;
            ushort4 o;
            if (i < n4x) v = Xf[i]; else v = Wf[i - n4x];
            bf16 a = __float2bfloat16(v.x); o.x = *(unsigned short*)&a;
            bf16 b = __float2bfloat16(v.y); o.y = *(unsigned short*)&b;
            bf16 c = __float2bfloat16(v.z); o.z = *(unsigned short*)&c;
            bf16 d = __float2bfloat16(v.w); o.w = *(unsigned short*)&d;
            if (i < n4x) Xb[i] = o; else Wb[i - n4x] = o;
        }
        return;
    }
    __shared__ int cntA[NBK], cntB[NBK], pre1[NBK], tot[NBK], sc[NBK], loff[NBK], gbase[NBK];
    __shared__ unsigned stage[CHUNK];
    int sub = t >> 7;  // 0 or 1
    int base = blockIdx.x * CHUNK;
    unsigned p[16];
    int rk[16];
#pragma unroll
    for (int k = 0; k < 16; ++k) {
        int i = base + k * 256 + t;
        p[k] = (i < nnz) ? (((unsigned)src[i] << 15) | (unsigned)dst[i]) : 0xFFFFFFFFu;
    }

    // ---- phase E: bucket by dst>>7 ----
    cntA[t] = 0; cntB[t] = 0;
    __syncthreads();
#pragma unroll
    for (int k = 0; k < 16; ++k)
        if (p[k] != 0xFFFFFFFFu) {
            int b = (p[k] >> ESHIFT) & 0xFF;
            rk[k] = atomicAdd(sub ? &cntB[b] : &cntA[b], 1);
        }
    __syncthreads();
    {
        int a = cntA[t], b = cntB[t];
        pre1[t] = a; tot[t] = a + b; sc[t] = a + b;
    }
    __syncthreads();
    for (int o = 1; o < NBK; o <<= 1) { int x = (t >= o) ? sc[t - o] : 0; __syncthreads(); sc[t] += x; __syncthreads(); }
    loff[t] = sc[t] - tot[t];
    gbase[t] = (tot[t] > 0) ? atomicAdd(&bcur_e[t], tot[t]) : 0;
    __syncthreads();
#pragma unroll
    for (int k = 0; k < 16; ++k)
        if (p[k] != 0xFFFFFFFFu) {
            int b = (p[k] >> ESHIFT) & 0xFF;
            stage[loff[b] + rk[k] + (sub ? pre1[b] : 0)] = p[k];
        }
    __syncthreads();
    {
        int wid = t >> 6, ln = t & 63;
        for (int b2 = wid; b2 < NBK; b2 += 4) {
            int n = tot[b2], lo = loff[b2], gb = gbase[b2];
            for (int idx = ln; idx < n; idx += 64) pairs_e[gb + idx] = stage[lo + idx];
        }
    }
    __syncthreads();

    // ---- phase V: bucket by src>>9 (= p>>24) ----
    cntA[t] = 0; cntB[t] = 0;
    __syncthreads();
#pragma unroll
    for (int k = 0; k < 16; ++k)
        if (p[k] != 0xFFFFFFFFu) {
            int b = p[k] >> 24;
            rk[k] = atomicAdd(sub ? &cntB[b] : &cntA[b], 1);
        }
    __syncthreads();
    {
        int a = cntA[t], b = cntB[t];
        pre1[t] = a; tot[t] = a + b; sc[t] = a + b;
    }
    __syncthreads();
    for (int o = 1; o < NBK; o <<= 1) { int x = (t >= o) ? sc[t - o] : 0; __syncthreads(); sc[t] += x; __syncthreads(); }
    loff[t] = sc[t] - tot[t];
    gbase[t] = (tot[t] > 0) ? atomicAdd(&bcur_v[t], tot[t]) : 0;
    __syncthreads();
#pragma unroll
    for (int k = 0; k < 16; ++k)
        if (p[k] != 0xFFFFFFFFu) {
            int b = p[k] >> 24;
            stage[loff[b] + rk[k] + (sub ? pre1[b] : 0)] = p[k];
        }
    __syncthreads();
    {
        int wid = t >> 6, ln = t & 63;
        for (int b2 = wid; b2 < NBK; b2 += 4) {
            int n = tot[b2], lo = loff[b2], gb = gbase[b2];
            for (int idx = ln; idx < n; idx += 64) pairs_v[gb + idx] = stage[lo + idx];
        }
    }
}

// ---------------- per-bucket CSR build: split-counter histogram, rank-based placement ----------------
__global__ __launch_bounds__(1024) void build_csr(const unsigned* __restrict__ pairs_e, const int* __restrict__ bcur_e,
                                                  int* __restrict__ off_e, int* __restrict__ end_e, int* __restrict__ e_src,
                                                  const unsigned* __restrict__ pairs_v, const int* __restrict__ bcur_v,
                                                  int* __restrict__ off_v, int* __restrict__ end_v, int* __restrict__ v_edge,
                                                  int* __restrict__ deg_v) {
    __shared__ int cA[2048], cB[2048], sc2[512], eoff[512];
    int t = threadIdx.x;
    cA[t] = 0; cA[t + 1024] = 0;
    __syncthreads();
    if ((int)blockIdx.x < NBE) {
        int b = blockIdx.x;
        int lo = b * CAPE, hi = bcur_e[b];
        int sub = t >> 7;  // 0..7 over 128 counters
        unsigned pv[12];
        int rk[12];
        int kk = 0;
        for (int i = lo + t; i < hi; i += 1024, ++kk) {
            unsigned p = pairs_e[i];
            pv[kk] = p;
            rk[kk] = atomicAdd(&cA[sub * 128 + (p & 127)], 1);
        }
        __syncthreads();
        if (t < 128) {
            int run = 0;
#pragma unroll
            for (int s = 0; s < 8; ++s) { cB[s * 128 + t] = run; run += cA[s * 128 + t]; }
            sc2[t] = run;
        }
        __syncthreads();
        for (int o = 1; o < 128; o <<= 1) {
            int x = 0;
            if (t < 128 && t >= o) x = sc2[t - o];
            __syncthreads();
            if (t < 128) sc2[t] += x;
            __syncthreads();
        }
        if (t < 128) {
            int totalb = cB[7 * 128 + t] + cA[7 * 128 + t];
            int ex = sc2[t] - totalb;
            eoff[t] = ex;
            int e = (b << ESHIFT) + t;
            if (e < NE) { off_e[e] = lo + ex; end_e[e] = lo + ex + totalb; }
        }
        __syncthreads();
        for (int k = 0; k < kk; ++k) {
            int bkt = pv[k] & 127;
            int pos = lo + eoff[bkt] + cB[sub * 128 + bkt] + rk[k];
            e_src[pos] = (int)(pv[k] >> 15);
        }
    } else {
        int b = blockIdx.x - NBE;
        int lo = b * CAPV, hi = bcur_v[b];
        int sub = t >> 8;  // 0..3 over 512 counters
        unsigned pv[9];
        int rk[9];
        int kk = 0;
        for (int i = lo + t; i < hi; i += 1024, ++kk) {
            unsigned p = pairs_v[i];
            pv[kk] = p;
            rk[kk] = atomicAdd(&cA[sub * 512 + ((p >> 15) & 511)], 1);
        }
        __syncthreads();
        if (t < 512) {
            int run = 0;
#pragma unroll
            for (int s = 0; s < 4; ++s) { cB[s * 512 + t] = run; run += cA[s * 512 + t]; }
            sc2[t] = run;
        }
        __syncthreads();
        for (int o = 1; o < 512; o <<= 1) {
            int x = 0;
            if (t < 512 && t >= o) x = sc2[t - o];
            __syncthreads();
            if (t < 512) sc2[t] += x;
            __syncthreads();
        }
        if (t < 512) {
            int totalb = cB[3 * 512 + t] + cA[3 * 512 + t];
            int ex = sc2[t] - totalb;
            eoff[t] = ex;
            int v = (b << VSHIFT) + t;
            if (v < NV) { off_v[v] = lo + ex; end_v[v] = lo + ex + totalb; deg_v[v] = totalb; }
        }
        __syncthreads();
        for (int k = 0; k < kk; ++k) {
            int bkt = (pv[k] >> 15) & 511;
            int pos = lo + eoff[bkt] + cB[sub * 512 + bkt] + rk[k];
            v_edge[pos] = (int)(pv[k] & 0x7FFF);
        }
    }
}

// ---------------- fused edge aggregation + GEMM (S-tile in LDS) ----------------
// block = 256 threads = 4 waves; 16 edges/block; wave w aggregates edges w*4..w*4+3,
// then the 4 waves do the 16x128 @ 128x128^T MFMA GEMM from the LDS S-tile.
__global__ __launch_bounds__(256) void edge_fused(const uint4* __restrict__ Xq, const int* __restrict__ off_e,
                                                  const int* __restrict__ end_e,
                                                  const int* __restrict__ e_src, const int* __restrict__ deg_v,
                                                  const bf16* __restrict__ Wb, const float* __restrict__ bias,
                                                  bf16* __restrict__ Y) {
    __shared__ short Stile[16][136];  // padded: 272B row stride -> conflict-free frag reads
    __shared__ float betaL[16];
    int t = threadIdx.x;
    int w = t >> 6, lane = t & 63;
    int g = lane >> 4, l16 = lane & 15;
    int mBase = blockIdx.x * 16;

    for (int ei = 0; ei < 4; ++ei) {
        int le = w * 4 + ei;
        int e = mBase + le;
        int start = off_e[e], end = end_e[e];
        float acc[8] = {0.f, 0.f, 0.f, 0.f, 0.f, 0.f, 0.f, 0.f};
        float degsum = 0.f;
        int j = start;
        for (; j + 16 <= end; j += 16) {
            int s0 = e_src[j + g];
            int s1 = e_src[j + 4 + g];
            int s2 = e_src[j + 8 + g];
            int s3 = e_src[j + 12 + g];
            uint4 x0 = Xq[(size_t)s0 * 16 + l16];
            uint4 x1 = Xq[(size_t)s1 * 16 + l16];
            uint4 x2 = Xq[(size_t)s2 * 16 + l16];
            uint4 x3 = Xq[(size_t)s3 * 16 + l16];
            degsum += (float)(deg_v[s0] + deg_v[s1] + deg_v[s2] + deg_v[s3]);
            accum8(acc, x0);
            accum8(acc, x1);
            accum8(acc, x2);
            accum8(acc, x3);
        }
        for (; j < end; j += 4) {
            int idx = j + g;
            if (idx < end) {
                int s = e_src[idx];
                uint4 x = Xq[(size_t)s * 16 + l16];
                degsum += (float)deg_v[s];
                accum8(acc, x);
            }
        }
#pragma unroll
        for (int i = 0; i < 8; ++i) {
            acc[i] += __shfl_xor(acc[i], 16);
            acc[i] += __shfl_xor(acc[i], 32);
        }
        degsum += __shfl_xor(degsum, 16);
        degsum += __shfl_xor(degsum, 32);

        float cntf = (float)(end - start);
        float Des = degsum / (cntf + 1.0f);
        float De = (Des > 0.f) ? rsqrtf(fmaxf(Des, 1e-30f)) : 1.0f;
        float scale = De / fmaxf(cntf, 1.0f);
        if (g == 0) {
            uint4 o;
            o.x = pk2(acc[0] * scale, acc[1] * scale);
            o.y = pk2(acc[2] * scale, acc[3] * scale);
            o.z = pk2(acc[4] * scale, acc[5] * scale);
            o.w = pk2(acc[6] * scale, acc[7] * scale);
            *(uint4*)&Stile[le][l16 * 8] = o;
            if (l16 == 0) betaL[le] = (cntf > 0.f) ? De : 0.f;
        }
    }
    __syncthreads();

    // GEMM phase: wave w computes output column tiles nt = 2w, 2w+1
    const short* Ws = (const short*)Wb;
    int quad = g;
    frag_ab a[4];
#pragma unroll
    for (int kt = 0; kt < 4; ++kt)
        a[kt] = *(const frag_ab*)&Stile[l16][kt * 32 + quad * 8];
    float beta_r[4];
#pragma unroll
    for (int r = 0; r < 4; ++r) beta_r[r] = betaL[quad * 4 + r];

#pragma unroll
    for (int nn = 0; nn < 2; ++nn) {
        int nt = w * 2 + nn;
        frag_cd acc = {0.f, 0.f, 0.f, 0.f};
#pragma unroll
        for (int kt = 0; kt < 4; ++kt) {
            frag_ab bfr = *(const frag_ab*)(Ws + (size_t)(nt * 16 + l16) * DD + kt * 32 + quad * 8);
            acc = __builtin_amdgcn_mfma_f32_16x16x32_bf16(a[kt], bfr, acc, 0, 0, 0);
        }
        float bv = bias[nt * 16 + l16];
#pragma unroll
        for (int r = 0; r < 4; ++r) {
            int row = mBase + quad * 4 + r;
            float v = acc[r] + beta_r[r] * bv;
            Y[(size_t)row * DD + nt * 16 + l16] = __float2bfloat16(v);
        }
    }
}

// ---------------- vertex aggregation + norm + relu: 16B loads, x16 unroll ----------------
__global__ __launch_bounds__(256) void vertex_agg(const uint4* __restrict__ Yq, const int* __restrict__ off_v,
                                                  const int* __restrict__ end_v,
                                                  const int* __restrict__ v_edge, float* __restrict__ out) {
    int wave = (blockIdx.x * blockDim.x + threadIdx.x) >> 6;
    int lane = threadIdx.x & 63;
    if (wave >= NV) return;
    int g = lane >> 4, l16 = lane & 15;
    int start = off_v[wave], end = end_v[wave];
    float acc[8] = {0.f, 0.f, 0.f, 0.f, 0.f, 0.f, 0.f, 0.f};
    int j = start;
    for (; j + 16 <= end; j += 16) {
        int e0 = v_edge[j + g];
        int e1 = v_edge[j + 4 + g];
        int e2 = v_edge[j + 8 + g];
        int e3 = v_edge[j + 12 + g];
        uint4 y0 = Yq[(size_t)e0 * 16 + l16];
        uint4 y1 = Yq[(size_t)e1 * 16 + l16];
        uint4 y2 = Yq[(size_t)e2 * 16 + l16];
        uint4 y3 = Yq[(size_t)e3 * 16 + l16];
        accum8(acc, y0);
        accum8(acc, y1);
        accum8(acc, y2);
        accum8(acc, y3);
    }
    for (; j < end; j += 4) {
        int idx = j + g;
        if (idx < end) {
            int e = v_edge[idx];
            uint4 y = Yq[(size_t)e * 16 + l16];
            accum8(acc, y);
        }
    }
#pragma unroll
    for (int i = 0; i < 8; ++i) {
        acc[i] += __shfl_xor(acc[i], 16);
        acc[i] += __shfl_xor(acc[i], 32);
    }
    int deg = end - start;
    float dvn = (deg > 0) ? rsqrtf((float)deg) : 0.f;
    if (g == 0) {
        float4 o1, o2;
        o1.x = fmaxf(acc[0] * dvn, 0.f);
        o1.y = fmaxf(acc[1] * dvn, 0.f);
        o1.z = fmaxf(acc[2] * dvn, 0.f);
        o1.w = fmaxf(acc[3] * dvn, 0.f);
        o2.x = fmaxf(acc[4] * dvn, 0.f);
        o2.y = fmaxf(acc[5] * dvn, 0.f);
        o2.z = fmaxf(acc[6] * dvn, 0.f);
        o2.w = fmaxf(acc[7] * dvn, 0.f);
        float4* op = (float4*)(out + (size_t)wave * DD + l16 * 8);
        op[0] = o1;
        op[1] = o2;
    }
}

extern "C" void kernel_launch(void* const* d_in, const int* in_sizes, int n_in,
                              void* d_out, int out_size, void* d_ws, size_t ws_size,
                              hipStream_t stream) {
    const float* X = (const float*)d_in[0];
    const float* W = (const float*)d_in[1];
    const float* b = (const float*)d_in[2];
    const int* src = (const int*)d_in[3];
    const int* dst = (const int*)d_in[4];
    int nnz = in_sizes[3];

    char* ws = (char*)d_ws;
    size_t o = 0;
    auto take = [&](size_t bytes) -> char* {
        char* p = ws + o;
        o += (bytes + 255) & ~(size_t)255;
        return p;
    };
    int* bcur_e = (int*)take(NBK * 4);
    int* bcur_v = (int*)take(NBK * 4);
    int* off_e = (int*)take((size_t)NE * 4);
    int* end_e = (int*)take((size_t)NE * 4);
    int* off_v = (int*)take((size_t)NV * 4);
    int* end_v = (int*)take((size_t)NV * 4);
    int* deg_v = (int*)take((size_t)NV * 4);
    int* e_src = (int*)take((size_t)NBE * CAPE * 4);
    int* v_edge = (int*)take((size_t)NBV * CAPV * 4);
    unsigned* pairs_e = (unsigned*)take((size_t)NBE * CAPE * 4);
    unsigned* pairs_v = (unsigned*)take((size_t)NBV * CAPV * 4);
    bf16* Y = (bf16*)take((size_t)NE * DD * 2);
    bf16* Wb = (bf16*)take((size_t)DD * DD * 2);
    bf16* Xb = (bf16*)take((size_t)NV * DD * 2);
    (void)ws_size; (void)n_in; (void)out_size;

    int nchunk = (nnz + CHUNK - 1) / CHUNK;
    int ncvt = (NV * DD / 4 + DD * DD / 4 + 255) / 256;

    init_cur<<<1, NBK, 0, stream>>>(bcur_e, bcur_v);
    partition_and_cvt<<<nchunk + ncvt, 256, 0, stream>>>(src, dst, bcur_e, bcur_v, pairs_e, pairs_v, nnz,
                                                         (const float4*)X, (ushort4*)Xb,
                                                         (const float4*)W, (ushort4*)Wb);
    build_csr<<<NBE + NBV, 1024, 0, stream>>>(pairs_e, bcur_e, off_e, end_e, e_src,
                                              pairs_v, bcur_v, off_v, end_v, v_edge, deg_v);
    edge_fused<<<NE / 16, 256, 0, stream>>>((const uint4*)Xb, off_e, end_e, e_src, deg_v, Wb, b, Y);
    vertex_agg<<<NV * 64 / 256, 256, 0, stream>>>((const uint4*)Y, off_v, end_v, v_edge, (float*)d_out);
}

// Round 9
// 256.109 us; speedup vs baseline: 3.1397x; 1.0465x over previous
//
#include <hip/hip_runtime.h>
#include <hip/hip_bf16.h>

#define NV 100000
#define NE 20000
#define DD 128
#define ESHIFT 7          // e-bucket = dst>>7  -> 157 buckets
#define VSHIFT 9          // v-bucket = src>>9  -> 196 buckets
#define NBE 157
#define NBV 196
#define NBK 256
#define CHUNK 4096
#define CAPE 11264        // per-e-bucket capacity (mean 10240, sigma ~101)
#define CAPV 9216         // per-v-bucket capacity (mean 8192, sigma ~90)

using bf16 = __hip_bfloat16;

typedef __attribute__((ext_vector_type(8))) short frag_ab;
typedef __attribute__((ext_vector_type(4))) float frag_cd;

__device__ __forceinline__ float uas(unsigned u) { union { unsigned u; float f; } c; c.u = u; return c.f; }
__device__ __forceinline__ unsigned pk2(float lo, float hi) {
    bf16 l = __float2bfloat16(lo), h = __float2bfloat16(hi);
    return (unsigned)(*(unsigned short*)&l) | ((unsigned)(*(unsigned short*)&h) << 16);
}
__device__ __forceinline__ void accum8(float* a, uint4 x) {
    a[0] += uas(x.x << 16); a[1] += uas(x.x & 0xffff0000u);
    a[2] += uas(x.y << 16); a[3] += uas(x.y & 0xffff0000u);
    a[4] += uas(x.z << 16); a[5] += uas(x.z & 0xffff0000u);
    a[6] += uas(x.w << 16); a[7] += uas(x.w & 0xffff0000u);
}
__device__ __forceinline__ int wave_incl_scan(int v, int lane) {
#pragma unroll
    for (int o = 1; o < 64; o <<= 1) {
        int x = __shfl_up(v, o);
        if (lane >= o) v += x;
    }
    return v;
}

// ---------------- init per-bucket cursors ----------------
__global__ void init_cur(int* __restrict__ bcur_e, int* __restrict__ bcur_v) {
    int t = threadIdx.x;  // 256
    bcur_e[t] = t * CAPE;
    bcur_v[t] = t * CAPV;
}

// ---------------- fused: LDS-staged radix partition (wave-scan, contiguous flush) + cvt ----------------
__global__ __launch_bounds__(256) void partition_and_cvt(const int* __restrict__ src, const int* __restrict__ dst,
                                                         int* __restrict__ bcur_e, int* __restrict__ bcur_v,
                                                         unsigned* __restrict__ pairs_e, unsigned* __restrict__ pairs_v,
                                                         int nnz,
                                                         const float4* __restrict__ Xf, ushort4* __restrict__ Xb,
                                                         const float4* __restrict__ Wf, ushort4* __restrict__ Wb) {
    int nchunk = (nnz + CHUNK - 1) / CHUNK;
    int t = threadIdx.x;
    if ((int)blockIdx.x >= nchunk) {
        const int n4x = NV * DD / 4;
        const int n4w = DD * DD / 4;
        int i = ((int)blockIdx.x - nchunk) * 256 + t;
        if (i < n4x + n4w) {
            float4 v;
            ushort4 o;
            if (i < n4x) v = Xf[i]; else v = Wf[i - n4x];
            bf16 a = __float2bfloat16(v.x); o.x = *(unsigned short*)&a;
            bf16 b = __float2bfloat16(v.y); o.y = *(unsigned short*)&b;
            bf16 c = __float2bfloat16(v.z); o.z = *(unsigned short*)&c;
            bf16 d = __float2bfloat16(v.w); o.w = *(unsigned short*)&d;
            if (i < n4x) Xb[i] = o; else Wb[i - n4x] = o;
        }
        return;
    }
    __shared__ int cntA[NBK], cntB[NBK], pre1[NBK], loff[NBK], gbase[NBK], wsum[4];
    __shared__ int totValid;
    __shared__ unsigned stage[CHUNK];
    int sub = t >> 7;  // 0 or 1
    int lane = t & 63, wv = t >> 6;
    int base = blockIdx.x * CHUNK;
    unsigned p[16];
    int rk[16];
#pragma unroll
    for (int k = 0; k < 16; ++k) {
        int i = base + k * 256 + t;
        p[k] = (i < nnz) ? (((unsigned)src[i] << 15) | (unsigned)dst[i]) : 0xFFFFFFFFu;
    }

    // ---- phase E: bucket by dst>>7 ----
    cntA[t] = 0; cntB[t] = 0;
    __syncthreads();
#pragma unroll
    for (int k = 0; k < 16; ++k)
        if (p[k] != 0xFFFFFFFFu) {
            int b = (p[k] >> ESHIFT) & 0xFF;
            rk[k] = atomicAdd(sub ? &cntB[b] : &cntA[b], 1);
        }
    __syncthreads();
    {
        int a = cntA[t], bb = cntB[t];
        int tv = a + bb;
        pre1[t] = a;
        int incl = wave_incl_scan(tv, lane);
        if (lane == 63) wsum[wv] = incl;
        __syncthreads();
        if (t == 0) { int r = 0; for (int i = 0; i < 4; ++i) { int x = wsum[i]; wsum[i] = r; r += x; } }
        __syncthreads();
        int ex = incl - tv + wsum[wv];
        loff[t] = ex;
        gbase[t] = (tv > 0) ? atomicAdd(&bcur_e[t], tv) : 0;
        if (t == 255) totValid = ex + tv;
    }
    __syncthreads();
#pragma unroll
    for (int k = 0; k < 16; ++k)
        if (p[k] != 0xFFFFFFFFu) {
            int b = (p[k] >> ESHIFT) & 0xFF;
            stage[loff[b] + rk[k] + (sub ? pre1[b] : 0)] = p[k];
        }
    __syncthreads();
    for (int i = t; i < totValid; i += 256) {
        unsigned pp = stage[i];
        int b = (pp >> ESHIFT) & 0xFF;
        pairs_e[gbase[b] + i - loff[b]] = pp;
    }
    __syncthreads();

    // ---- phase V: bucket by src>>9 (= p>>24) ----
    cntA[t] = 0; cntB[t] = 0;
    __syncthreads();
#pragma unroll
    for (int k = 0; k < 16; ++k)
        if (p[k] != 0xFFFFFFFFu) {
            int b = p[k] >> 24;
            rk[k] = atomicAdd(sub ? &cntB[b] : &cntA[b], 1);
        }
    __syncthreads();
    {
        int a = cntA[t], bb = cntB[t];
        int tv = a + bb;
        pre1[t] = a;
        int incl = wave_incl_scan(tv, lane);
        if (lane == 63) wsum[wv] = incl;
        __syncthreads();
        if (t == 0) { int r = 0; for (int i = 0; i < 4; ++i) { int x = wsum[i]; wsum[i] = r; r += x; } }
        __syncthreads();
        int ex = incl - tv + wsum[wv];
        loff[t] = ex;
        gbase[t] = (tv > 0) ? atomicAdd(&bcur_v[t], tv) : 0;
        if (t == 255) totValid = ex + tv;
    }
    __syncthreads();
#pragma unroll
    for (int k = 0; k < 16; ++k)
        if (p[k] != 0xFFFFFFFFu) {
            int b = p[k] >> 24;
            stage[loff[b] + rk[k] + (sub ? pre1[b] : 0)] = p[k];
        }
    __syncthreads();
    for (int i = t; i < totValid; i += 256) {
        unsigned pp = stage[i];
        int b = pp >> 24;
        pairs_v[gbase[b] + i - loff[b]] = pp;
    }
}

// ---------------- per-bucket CSR build: split counters, wave scans, rank placement ----------------
__global__ __launch_bounds__(1024) void build_csr(const unsigned* __restrict__ pairs_e, const int* __restrict__ bcur_e,
                                                  int* __restrict__ off_e, int* __restrict__ end_e, int* __restrict__ e_src,
                                                  const unsigned* __restrict__ pairs_v, const int* __restrict__ bcur_v,
                                                  int* __restrict__ off_v, int* __restrict__ end_v, int* __restrict__ v_edge,
                                                  int* __restrict__ deg_v) {
    __shared__ int cA[2048], cB[2048], sc2[512], eoff[512], wsumS[8];
    int t = threadIdx.x;
    cA[t] = 0; cA[t + 1024] = 0;
    __syncthreads();
    if ((int)blockIdx.x < NBE) {
        int b = blockIdx.x;
        int lo = b * CAPE, hi = bcur_e[b];
        int sub = t >> 7;  // 0..7 over 128 counters
        unsigned pv[12];
        int rk[12];
        int kk = 0;
        for (int i = lo + t; i < hi; i += 1024, ++kk) {
            unsigned p = pairs_e[i];
            pv[kk] = p;
            rk[kk] = atomicAdd(&cA[sub * 128 + (p & 127)], 1);
        }
        __syncthreads();
        if (t < 128) {
            int run = 0;
#pragma unroll
            for (int s = 0; s < 8; ++s) { cB[s * 128 + t] = run; run += cA[s * 128 + t]; }
            sc2[t] = run;
        }
        __syncthreads();
        int incl = 0, myrun = 0;
        if (t < 128) {
            myrun = sc2[t];
            incl = wave_incl_scan(myrun, t & 63);
            if ((t & 63) == 63) wsumS[t >> 6] = incl;
        }
        __syncthreads();
        if (t == 0) { int r = 0; for (int i = 0; i < 2; ++i) { int x = wsumS[i]; wsumS[i] = r; r += x; } }
        __syncthreads();
        if (t < 128) {
            int ex = incl - myrun + wsumS[t >> 6];
            eoff[t] = ex;
            int e = (b << ESHIFT) + t;
            if (e < NE) { off_e[e] = lo + ex; end_e[e] = lo + ex + myrun; }
        }
        __syncthreads();
        for (int k = 0; k < kk; ++k) {
            int bkt = pv[k] & 127;
            int pos = lo + eoff[bkt] + cB[sub * 128 + bkt] + rk[k];
            e_src[pos] = (int)(pv[k] >> 15);
        }
    } else {
        int b = blockIdx.x - NBE;
        int lo = b * CAPV, hi = bcur_v[b];
        int sub = t >> 8;  // 0..3 over 512 counters
        unsigned pv[9];
        int rk[9];
        int kk = 0;
        for (int i = lo + t; i < hi; i += 1024, ++kk) {
            unsigned p = pairs_v[i];
            pv[kk] = p;
            rk[kk] = atomicAdd(&cA[sub * 512 + ((p >> 15) & 511)], 1);
        }
        __syncthreads();
        if (t < 512) {
            int run = 0;
#pragma unroll
            for (int s = 0; s < 4; ++s) { cB[s * 512 + t] = run; run += cA[s * 512 + t]; }
            sc2[t] = run;
        }
        __syncthreads();
        int incl = 0, myrun = 0;
        if (t < 512) {
            myrun = sc2[t];
            incl = wave_incl_scan(myrun, t & 63);
            if ((t & 63) == 63) wsumS[t >> 6] = incl;
        }
        __syncthreads();
        if (t == 0) { int r = 0; for (int i = 0; i < 8; ++i) { int x = wsumS[i]; wsumS[i] = r; r += x; } }
        __syncthreads();
        if (t < 512) {
            int ex = incl - myrun + wsumS[t >> 6];
            eoff[t] = ex;
            int v = (b << VSHIFT) + t;
            if (v < NV) { off_v[v] = lo + ex; end_v[v] = lo + ex + myrun; deg_v[v] = myrun; }
        }
        __syncthreads();
        for (int k = 0; k < kk; ++k) {
            int bkt = (pv[k] >> 15) & 511;
            int pos = lo + eoff[bkt] + cB[sub * 512 + bkt] + rk[k];
            v_edge[pos] = (int)(pv[k] & 0x7FFF);
        }
    }
}

// ---------------- fused edge aggregation + GEMM: group-per-edge, x8 unroll ----------------
// block = 256 = 4 waves = 16 groups of 16 lanes; group owns one edge (32 rows in flight/wave)
__global__ __launch_bounds__(256) void edge_fused(const uint4* __restrict__ Xq, const int* __restrict__ off_e,
                                                  const int* __restrict__ end_e,
                                                  const int* __restrict__ e_src, const int* __restrict__ deg_v,
                                                  const bf16* __restrict__ Wb, const float* __restrict__ bias,
                                                  bf16* __restrict__ Y) {
    __shared__ short Stile[16][136];  // 272B row stride -> 2-way aliasing only (free)
    __shared__ float betaL[16];
    int t = threadIdx.x;
    int w = t >> 6, lane = t & 63;
    int g = lane >> 4, l16 = lane & 15;
    int mBase = blockIdx.x * 16;
    int le = w * 4 + g;
    int e = mBase + le;
    int start = off_e[e], end = end_e[e];
    float acc[8] = {0.f, 0.f, 0.f, 0.f, 0.f, 0.f, 0.f, 0.f};
    float degsum = 0.f;
    int j = start;
    for (; j + 8 <= end; j += 8) {
        int s0 = e_src[j + 0], s1 = e_src[j + 1], s2 = e_src[j + 2], s3 = e_src[j + 3];
        int s4 = e_src[j + 4], s5 = e_src[j + 5], s6 = e_src[j + 6], s7 = e_src[j + 7];
        uint4 x0 = Xq[(size_t)s0 * 16 + l16];
        uint4 x1 = Xq[(size_t)s1 * 16 + l16];
        uint4 x2 = Xq[(size_t)s2 * 16 + l16];
        uint4 x3 = Xq[(size_t)s3 * 16 + l16];
        uint4 x4 = Xq[(size_t)s4 * 16 + l16];
        uint4 x5 = Xq[(size_t)s5 * 16 + l16];
        uint4 x6 = Xq[(size_t)s6 * 16 + l16];
        uint4 x7 = Xq[(size_t)s7 * 16 + l16];
        degsum += (float)(deg_v[s0] + deg_v[s1] + deg_v[s2] + deg_v[s3]
                        + deg_v[s4] + deg_v[s5] + deg_v[s6] + deg_v[s7]);
        accum8(acc, x0); accum8(acc, x1); accum8(acc, x2); accum8(acc, x3);
        accum8(acc, x4); accum8(acc, x5); accum8(acc, x6); accum8(acc, x7);
    }
    for (; j + 4 <= end; j += 4) {
        int s0 = e_src[j + 0], s1 = e_src[j + 1], s2 = e_src[j + 2], s3 = e_src[j + 3];
        uint4 x0 = Xq[(size_t)s0 * 16 + l16];
        uint4 x1 = Xq[(size_t)s1 * 16 + l16];
        uint4 x2 = Xq[(size_t)s2 * 16 + l16];
        uint4 x3 = Xq[(size_t)s3 * 16 + l16];
        degsum += (float)(deg_v[s0] + deg_v[s1] + deg_v[s2] + deg_v[s3]);
        accum8(acc, x0); accum8(acc, x1); accum8(acc, x2); accum8(acc, x3);
    }
    for (; j < end; ++j) {
        int s = e_src[j];
        uint4 x = Xq[(size_t)s * 16 + l16];
        degsum += (float)deg_v[s];
        accum8(acc, x);
    }
    float cntf = (float)(end - start);
    float Des = degsum / (cntf + 1.0f);
    float De = (Des > 0.f) ? rsqrtf(fmaxf(Des, 1e-30f)) : 1.0f;
    float scale = De / fmaxf(cntf, 1.0f);
    {
        uint4 o;
        o.x = pk2(acc[0] * scale, acc[1] * scale);
        o.y = pk2(acc[2] * scale, acc[3] * scale);
        o.z = pk2(acc[4] * scale, acc[5] * scale);
        o.w = pk2(acc[6] * scale, acc[7] * scale);
        *(uint4*)&Stile[le][l16 * 8] = o;
        if (l16 == 0) betaL[le] = (cntf > 0.f) ? De : 0.f;
    }
    __syncthreads();

    // GEMM phase: wave w computes output column tiles nt = 2w, 2w+1
    const short* Ws = (const short*)Wb;
    int quad = g;
    frag_ab a[4];
#pragma unroll
    for (int kt = 0; kt < 4; ++kt)
        a[kt] = *(const frag_ab*)&Stile[l16][kt * 32 + quad * 8];
    float beta_r[4];
#pragma unroll
    for (int r = 0; r < 4; ++r) beta_r[r] = betaL[quad * 4 + r];

#pragma unroll
    for (int nn = 0; nn < 2; ++nn) {
        int nt = w * 2 + nn;
        frag_cd acc2 = {0.f, 0.f, 0.f, 0.f};
#pragma unroll
        for (int kt = 0; kt < 4; ++kt) {
            frag_ab bfr = *(const frag_ab*)(Ws + (size_t)(nt * 16 + l16) * DD + kt * 32 + quad * 8);
            acc2 = __builtin_amdgcn_mfma_f32_16x16x32_bf16(a[kt], bfr, acc2, 0, 0, 0);
        }
        float bv = bias[nt * 16 + l16];
#pragma unroll
        for (int r = 0; r < 4; ++r) {
            int row = mBase + quad * 4 + r;
            float v = acc2[r] + beta_r[r] * bv;
            Y[(size_t)row * DD + nt * 16 + l16] = __float2bfloat16(v);
        }
    }
}

// ---------------- vertex aggregation: group-per-vertex, x8 unroll, no shfl ----------------
__global__ __launch_bounds__(256) void vertex_agg(const uint4* __restrict__ Yq, const int* __restrict__ off_v,
                                                  const int* __restrict__ end_v,
                                                  const int* __restrict__ v_edge, float* __restrict__ out) {
    int wave = (blockIdx.x * blockDim.x + threadIdx.x) >> 6;
    int lane = threadIdx.x & 63;
    int g = lane >> 4, l16 = lane & 15;
    int v = wave * 4 + g;
    if (v >= NV) return;
    int start = off_v[v], end = end_v[v];
    float acc[8] = {0.f, 0.f, 0.f, 0.f, 0.f, 0.f, 0.f, 0.f};
    int j = start;
    for (; j + 8 <= end; j += 8) {
        int e0 = v_edge[j + 0], e1 = v_edge[j + 1], e2 = v_edge[j + 2], e3 = v_edge[j + 3];
        int e4 = v_edge[j + 4], e5 = v_edge[j + 5], e6 = v_edge[j + 6], e7 = v_edge[j + 7];
        uint4 y0 = Yq[(size_t)e0 * 16 + l16];
        uint4 y1 = Yq[(size_t)e1 * 16 + l16];
        uint4 y2 = Yq[(size_t)e2 * 16 + l16];
        uint4 y3 = Yq[(size_t)e3 * 16 + l16];
        uint4 y4 = Yq[(size_t)e4 * 16 + l16];
        uint4 y5 = Yq[(size_t)e5 * 16 + l16];
        uint4 y6 = Yq[(size_t)e6 * 16 + l16];
        uint4 y7 = Yq[(size_t)e7 * 16 + l16];
        accum8(acc, y0); accum8(acc, y1); accum8(acc, y2); accum8(acc, y3);
        accum8(acc, y4); accum8(acc, y5); accum8(acc, y6); accum8(acc, y7);
    }
    for (; j + 4 <= end; j += 4) {
        int e0 = v_edge[j + 0], e1 = v_edge[j + 1], e2 = v_edge[j + 2], e3 = v_edge[j + 3];
        uint4 y0 = Yq[(size_t)e0 * 16 + l16];
        uint4 y1 = Yq[(size_t)e1 * 16 + l16];
        uint4 y2 = Yq[(size_t)e2 * 16 + l16];
        uint4 y3 = Yq[(size_t)e3 * 16 + l16];
        accum8(acc, y0); accum8(acc, y1); accum8(acc, y2); accum8(acc, y3);
    }
    for (; j < end; ++j) {
        int e = v_edge[j];
        uint4 y = Yq[(size_t)e * 16 + l16];
        accum8(acc, y);
    }
    int deg = end - start;
    float dvn = (deg > 0) ? rsqrtf((float)deg) : 0.f;
    float4 o1, o2;
    o1.x = fmaxf(acc[0] * dvn, 0.f);
    o1.y = fmaxf(acc[1] * dvn, 0.f);
    o1.z = fmaxf(acc[2] * dvn, 0.f);
    o1.w = fmaxf(acc[3] * dvn, 0.f);
    o2.x = fmaxf(acc[4] * dvn, 0.f);
    o2.y = fmaxf(acc[5] * dvn, 0.f);
    o2.z = fmaxf(acc[6] * dvn, 0.f);
    o2.w = fmaxf(acc[7] * dvn, 0.f);
    float4* op = (float4*)(out + (size_t)v * DD + l16 * 8);
    op[0] = o1;
    op[1] = o2;
}

extern "C" void kernel_launch(void* const* d_in, const int* in_sizes, int n_in,
                              void* d_out, int out_size, void* d_ws, size_t ws_size,
                              hipStream_t stream) {
    const float* X = (const float*)d_in[0];
    const float* W = (const float*)d_in[1];
    const float* b = (const float*)d_in[2];
    const int* src = (const int*)d_in[3];
    const int* dst = (const int*)d_in[4];
    int nnz = in_sizes[3];

    char* ws = (char*)d_ws;
    size_t o = 0;
    auto take = [&](size_t bytes) -> char* {
        char* p = ws + o;
        o += (bytes + 255) & ~(size_t)255;
        return p;
    };
    int* bcur_e = (int*)take(NBK * 4);
    int* bcur_v = (int*)take(NBK * 4);
    int* off_e = (int*)take((size_t)NE * 4);
    int* end_e = (int*)take((size_t)NE * 4);
    int* off_v = (int*)take((size_t)NV * 4);
    int* end_v = (int*)take((size_t)NV * 4);
    int* deg_v = (int*)take((size_t)NV * 4);
    int* e_src = (int*)take((size_t)NBE * CAPE * 4);
    int* v_edge = (int*)take((size_t)NBV * CAPV * 4);
    unsigned* pairs_e = (unsigned*)take((size_t)NBE * CAPE * 4);
    unsigned* pairs_v = (unsigned*)take((size_t)NBV * CAPV * 4);
    bf16* Y = (bf16*)take((size_t)NE * DD * 2);
    bf16* Wb = (bf16*)take((size_t)DD * DD * 2);
    bf16* Xb = (bf16*)take((size_t)NV * DD * 2);
    (void)ws_size; (void)n_in; (void)out_size;

    int nchunk = (nnz + CHUNK - 1) / CHUNK;
    int ncvt = (NV * DD / 4 + DD * DD / 4 + 255) / 256;

    init_cur<<<1, NBK, 0, stream>>>(bcur_e, bcur_v);
    partition_and_cvt<<<nchunk + ncvt, 256, 0, stream>>>(src, dst, bcur_e, bcur_v, pairs_e, pairs_v, nnz,
                                                         (const float4*)X, (ushort4*)Xb,
                                                         (const float4*)W, (ushort4*)Wb);
    build_csr<<<NBE + NBV, 1024, 0, stream>>>(pairs_e, bcur_e, off_e, end_e, e_src,
                                              pairs_v, bcur_v, off_v, end_v, v_edge, deg_v);
    edge_fused<<<NE / 16, 256, 0, stream>>>((const uint4*)Xb, off_e, end_e, e_src, deg_v, Wb, b, Y);
    vertex_agg<<<(NV / 4 * 64) / 256, 256, 0, stream>>>((const uint4*)Y, off_v, end_v, v_edge, (float*)d_out);
}